// Round 14
// baseline (869.701 us; speedup 1.0000x reference)
//
// MultiheadSelectiveAttentionWithTokenPruning — MI355X round 14
// (r10 proven base: no flash swizzle [r13: conflict counter -84% but
//  wall-clock +13 µs — conflicts were off critical path], no global_load_lds
//  [suspect in r11/r12 container kills]. Safe launch-structure fusions only.)
//
// Pipeline (all on `stream`, graph-capture safe, no statics):
//  1  cast_x      : X fp32 -> Xhi/Xlo bf16 (split for bf16x3 GEMM)
//  2  cast_w      : ONE launch, z in {0..3} -> W^T bf16 (hi[+lo for Wq/Wk])
//  3  gemm split  : Yq = X@Wq  (hi*hi + hi*lo + lo*hi)  ~fp32 accuracy
//  4  gemm split  : Yk = X@Wk
//  5  gemm fused  : Vb = bf16(X@Wv) written directly in (B,H,N,Dh) layout
//                   (lnpackV eliminated: it was a pure cast; f2b(acc) in the
//                   gemm epilogue is bit-identical, saves 32 MiB round-trip)
//  6  lnpack      : LN(Yq) -> Qb bf16 + q0s fp32 (head-0 selection)
//  7  lnpack      : LN(Yk) -> Kb + k0s
//  8  s_kernel    : S[b,n,m] = relu(q0s.k0s/8), causal/diag/col0-zeroed
//  9  p_kernel    : column partial sums of S rows 0..1023 (8 chunks)
// 10  FUSED       : evict (2 blocks, r9-proven 4-wave code) ∥ flash part 1
//                   (512 blocks, q<1024: evictions all occur at i>=1024 so
//                   the prune mask is vacuous). Evict-bound at ~365 µs.
// 11  flash2      : q-tiles j=16..31 (needs evt).
// 12  gemm        : out = Ob @ Wo -> d_out fp32
//
// ws overlays: Ob reuses Xhi slot (dead after step 5); S reuses Yq+Yk slots
// (dead after steps 6/7). Peak ws ~107.1 MB.

#include <hip/hip_runtime.h>

#define B_    2
#define N_    2048
#define D_    1024
#define H_    16
#define DH_   64
#define M_    2048
#define ROWS_ 4096
#define BUD_  1024

typedef unsigned short u16;
typedef unsigned int   u32;
typedef unsigned long long u64;
typedef __attribute__((ext_vector_type(8))) short short8;
typedef __attribute__((ext_vector_type(4))) float floatx4;

__device__ __forceinline__ u16 f2b(float f) {
    u32 u = __float_as_uint(f);
    return (u16)((u + 0x7FFFu + ((u >> 16) & 1u)) >> 16);   // RNE
}
__device__ __forceinline__ float b2f(u16 h) {
    return __uint_as_float(((u32)h) << 16);
}

// ---------------------------------------------------------------- cast X
__global__ __launch_bounds__(256) void cast_x_kernel(
    const float* __restrict__ X, u16* __restrict__ Xhi, u16* __restrict__ Xlo)
{
    int idx = (blockIdx.x * 256 + threadIdx.x) * 4;
    float4 v = *(const float4*)&X[idx];
    u16 h0 = f2b(v.x), h1 = f2b(v.y), h2 = f2b(v.z), h3 = f2b(v.w);
    ushort4 hv; hv.x = h0; hv.y = h1; hv.z = h2; hv.w = h3;
    *(ushort4*)&Xhi[idx] = hv;
    ushort4 lv;
    lv.x = f2b(v.x - b2f(h0)); lv.y = f2b(v.y - b2f(h1));
    lv.z = f2b(v.z - b2f(h2)); lv.w = f2b(v.w - b2f(h3));
    *(ushort4*)&Xlo[idx] = lv;
}

// ------------------------------------ cast + transpose all 4 W (z-select)
__global__ __launch_bounds__(1024) void cast_w_all_kernel(
    const float* __restrict__ Wq, const float* __restrict__ Wk,
    const float* __restrict__ Wv, const float* __restrict__ Wo,
    u16* __restrict__ Wqh, u16* __restrict__ Wql,
    u16* __restrict__ Wkh, u16* __restrict__ Wkl,
    u16* __restrict__ Wvh, u16* __restrict__ Woh)
{
    const float* W; u16* Whi; u16* Wlo; int do_lo;
    switch (blockIdx.z) {
        case 0:  W = Wq; Whi = Wqh; Wlo = Wql; do_lo = 1; break;
        case 1:  W = Wk; Whi = Wkh; Wlo = Wkl; do_lo = 1; break;
        case 2:  W = Wv; Whi = Wvh; Wlo = nullptr; do_lo = 0; break;
        default: W = Wo; Whi = Woh; Wlo = nullptr; do_lo = 0; break;
    }
    __shared__ float tile[32][33];
    int tx = threadIdx.x, ty = threadIdx.y;
    int x = blockIdx.x * 32 + tx, y = blockIdx.y * 32 + ty;
    tile[ty][tx] = W[(size_t)y * D_ + x];
    __syncthreads();
    float v = tile[tx][ty];
    int n = blockIdx.x * 32 + ty, k = blockIdx.y * 32 + tx;
    u16 h = f2b(v);
    Whi[(size_t)n * D_ + k] = h;
    if (do_lo) Wlo[(size_t)n * D_ + k] = f2b(v - b2f(h));
}

// ------------------------------------------------------------- GEMM
// C[4096][1024] = A[4096][1024] @ Bt^T   (Bt stored [n][k])
// mode 1: C = Ah*Bh + Ah*Bl + Al*Bh  (bf16x3 split, ~fp32 precision)
// If Cb != nullptr: write bf16(acc) directly in (B,H,N,Dh) packed layout
// (fused lnpackV cast; bit-identical to lnpack with do_ln=0).
__global__ __launch_bounds__(256) void gemm_kernel(
    const u16* __restrict__ Ah, const u16* __restrict__ Al,
    const u16* __restrict__ Bh, const u16* __restrict__ Bl,
    int mode, float* __restrict__ C, u16* __restrict__ Cb)
{
    __shared__ __align__(16) u16 sAh[128 * 32];
    __shared__ __align__(16) u16 sBh[128 * 32];
    __shared__ __align__(16) u16 sAl[128 * 32];
    __shared__ __align__(16) u16 sBl[128 * 32];
    int tid = threadIdx.x;
    int lane = tid & 63, wv = tid >> 6;
    int wr = wv >> 1, wc = wv & 1;
    int quad = lane >> 4, l16 = lane & 15;
    int m0 = blockIdx.y * 128, n0 = blockIdx.x * 128;

    floatx4 acc[4][4];
    floatx4 zero = {0.f, 0.f, 0.f, 0.f};
#pragma unroll
    for (int i = 0; i < 4; ++i)
#pragma unroll
        for (int j = 0; j < 4; ++j) acc[i][j] = zero;

    for (int k0 = 0; k0 < 1024; k0 += 32) {
#pragma unroll
        for (int it = 0; it < 2; ++it) {
            int e = (tid + it * 256) * 8;
            int r = e >> 5, c = e & 31;
            *(uint4*)&sAh[e] = *(const uint4*)&Ah[(size_t)(m0 + r) * 1024 + k0 + c];
            *(uint4*)&sBh[e] = *(const uint4*)&Bh[(size_t)(n0 + r) * 1024 + k0 + c];
            if (mode) {
                *(uint4*)&sAl[e] = *(const uint4*)&Al[(size_t)(m0 + r) * 1024 + k0 + c];
                *(uint4*)&sBl[e] = *(const uint4*)&Bl[(size_t)(n0 + r) * 1024 + k0 + c];
            }
        }
        __syncthreads();
        short8 ah[4], al[4], bh[4], bl[4];
#pragma unroll
        for (int x = 0; x < 4; ++x) {
            int ra = (wr * 64 + x * 16 + l16) * 32 + quad * 8;
            int rb = (wc * 64 + x * 16 + l16) * 32 + quad * 8;
            ah[x] = *(const short8*)&sAh[ra];
            bh[x] = *(const short8*)&sBh[rb];
            if (mode) {
                al[x] = *(const short8*)&sAl[ra];
                bl[x] = *(const short8*)&sBl[rb];
            }
        }
#pragma unroll
        for (int mi = 0; mi < 4; ++mi)
#pragma unroll
            for (int ni = 0; ni < 4; ++ni) {
                acc[mi][ni] = __builtin_amdgcn_mfma_f32_16x16x32_bf16(
                    ah[mi], bh[ni], acc[mi][ni], 0, 0, 0);
                if (mode) {
                    acc[mi][ni] = __builtin_amdgcn_mfma_f32_16x16x32_bf16(
                        ah[mi], bl[ni], acc[mi][ni], 0, 0, 0);
                    acc[mi][ni] = __builtin_amdgcn_mfma_f32_16x16x32_bf16(
                        al[mi], bh[ni], acc[mi][ni], 0, 0, 0);
                }
            }
        __syncthreads();
    }
    // C/D layout: col = lane&15, row = (lane>>4)*4 + reg   [verified m89/m91]
#pragma unroll
    for (int mi = 0; mi < 4; ++mi)
#pragma unroll
        for (int ni = 0; ni < 4; ++ni)
#pragma unroll
            for (int r = 0; r < 4; ++r) {
                int row = m0 + wr * 64 + mi * 16 + quad * 4 + r;
                int col = n0 + wc * 64 + ni * 16 + l16;
                if (Cb) {
                    int b = row >> 11, n = row & 2047;
                    int h = col >> 6, dh = col & 63;
                    Cb[(((size_t)b * H_ + h) * N_ + n) * DH_ + dh] =
                        f2b(acc[mi][ni][r]);
                } else {
                    C[(size_t)row * 1024 + col] = acc[mi][ni][r];
                }
            }
}

// ----------------------------------------------------- LayerNorm + pack
__global__ __launch_bounds__(256) void lnpack_kernel(
    const float* __restrict__ Y, const float* __restrict__ gamma,
    const float* __restrict__ beta, u16* __restrict__ Pk,
    float* __restrict__ head0)
{
    int r = blockIdx.x;
    int tid = threadIdx.x;
    float4 v = *(const float4*)&Y[(size_t)r * D_ + tid * 4];
    float mu, rsig;
    __shared__ float sS[4], sQ[4];
    {
        float s = v.x + v.y + v.z + v.w;
        float q = v.x * v.x + v.y * v.y + v.z * v.z + v.w * v.w;
#pragma unroll
        for (int d = 1; d < 64; d <<= 1) { s += __shfl_xor(s, d); q += __shfl_xor(q, d); }
        if ((tid & 63) == 0) { sS[tid >> 6] = s; sQ[tid >> 6] = q; }
        __syncthreads();
        s = sS[0] + sS[1] + sS[2] + sS[3];
        q = sQ[0] + sQ[1] + sQ[2] + sQ[3];
        mu = s * (1.f / 1024.f);
        float var = q * (1.f / 1024.f) - mu * mu;
        rsig = rsqrtf(var + 1e-5f);
    }
    int b = r >> 11, n = r & 2047;
    float xs[4] = {v.x, v.y, v.z, v.w};
#pragma unroll
    for (int j = 0; j < 4; ++j) {
        int c = tid * 4 + j;
        float val = (xs[j] - mu) * rsig * gamma[c] + beta[c];
        int h = c >> 6, dh = c & 63;
        Pk[(((size_t)b * H_ + h) * N_ + n) * DH_ + dh] = f2b(val);
        if (c < 64) head0[(size_t)r * 64 + c] = val;
    }
}

// -------------------------------------------- head-0 selection scores S
__global__ void s_kernel(const float* __restrict__ q0,
                         const float* __restrict__ k0, float* __restrict__ S)
{
    int b = blockIdx.z;
    int n0 = blockIdx.y * 16, m0 = blockIdx.x * 16;
    int tx = threadIdx.x, ty = threadIdx.y;
    int n = n0 + ty, m = m0 + tx;
    float* out = S + ((size_t)b * N_ + n) * M_ + m;
    if (m0 > n0 + 15) { *out = 0.f; return; }   // fully above diagonal
    __shared__ float sq[16][65], sk[16][65];
    int tid = ty * 16 + tx;
    {
        int rr = tid >> 4, cc = (tid & 15) * 4;
        float4 qa = *(const float4*)&q0[((size_t)b * N_ + n0 + rr) * 64 + cc];
        sq[rr][cc] = qa.x; sq[rr][cc + 1] = qa.y; sq[rr][cc + 2] = qa.z; sq[rr][cc + 3] = qa.w;
        float4 ka = *(const float4*)&k0[((size_t)b * N_ + m0 + rr) * 64 + cc];
        sk[rr][cc] = ka.x; sk[rr][cc + 1] = ka.y; sk[rr][cc + 2] = ka.z; sk[rr][cc + 3] = ka.w;
    }
    __syncthreads();
    float acc = 0.f;
#pragma unroll 8
    for (int d = 0; d < 64; ++d) acc += sq[ty][d] * sk[tx][d];
    // causal (m>n) -> relu(-inf)=0 ; diagonal m==n -> 0 ; col 0 -> 0
    float val;
    if (m < n && m != 0) val = fmaxf(acc * 0.125f, 0.f); else val = 0.f;
    *out = val;
}

// -------------------------------- partial column sums of S rows 0..1023
__global__ __launch_bounds__(256) void p_kernel(const float* __restrict__ S,
                                                float* __restrict__ P)
{
    int b = blockIdx.z, c = blockIdx.y;
    int m = blockIdx.x * 256 + threadIdx.x;
    const float* base = S + ((size_t)b * N_ + c * 128) * M_ + m;
    float s = 0.f;
    for (int j = 0; j < 128; ++j) s += base[(size_t)j * M_];
    P[((size_t)b * 8 + c) * M_ + m] = s;
}

// --------------------------------------------- sequential greedy eviction
// (r9-proven 4-wave code, byte-identical logic)
__device__ __forceinline__ void vsel(float& va, u32& la, float vb, u32 lb) {
    bool tk = vb > va;
    va = tk ? vb : va;
    la = tk ? lb : la;
}

template<int CTRL, int RMASK>
__device__ __forceinline__ void dpp_max_pack(float& v, u32& lo) {
    int hi = __float_as_int(v);
    int hi_o = __builtin_amdgcn_update_dpp(hi, hi, CTRL, RMASK, 0xF, false);
    int lo_o = __builtin_amdgcn_update_dpp((int)lo, (int)lo, CTRL, RMASK, 0xF, false);
    long long a = (long long)((((u64)(u32)hi) << 32) | lo);
    long long b = (long long)((((u64)(u32)hi_o) << 32) | (u32)lo_o);
    bool tk = b > a;
    v = tk ? __int_as_float(hi_o) : v;
    lo = tk ? (u32)lo_o : lo;
}

__device__ __forceinline__ void wave_argmax_to63(float& v, u32& lo) {
    dpp_max_pack<0x121, 0xF>(v, lo);   // row_ror:1
    dpp_max_pack<0x122, 0xF>(v, lo);   // row_ror:2
    dpp_max_pack<0x124, 0xF>(v, lo);   // row_ror:4
    dpp_max_pack<0x128, 0xF>(v, lo);   // row_ror:8
    dpp_max_pack<0x142, 0xA>(v, lo);   // row_bcast15 -> rows 1,3
    dpp_max_pack<0x143, 0xC>(v, lo);   // row_bcast31 -> rows 2,3
}

#define GLOAD(dst, voff, ptr, imm)                                    \
    asm volatile("global_load_dwordx4 %0, %1, %2 offset:" #imm        \
                 : "=v"(dst) : "v"(voff), "s"(ptr) : "memory")

#define ISSUE2(bank, row)                                             \
    {                                                                 \
        u32 r_ = (u32)((row) < 2047 ? (row) : 2047);                  \
        u32 vo = wbyte + r_ * 8192u;                                  \
        GLOAD(bank[0], vo, Sb, 0);                                    \
        GLOAD(bank[1], vo, Sb, 1024);                                 \
    }

#define VWAIT6()                                                      \
    do { asm volatile("s_waitcnt vmcnt(6)" ::: "memory");             \
         __builtin_amdgcn_sched_barrier(0); } while (0)
#define VWAIT0()                                                      \
    do { asm volatile("s_waitcnt vmcnt(0)" ::: "memory");             \
         __builtin_amdgcn_sched_barrier(0); } while (0)

__device__ __forceinline__ void evict_step4(
    int i, int t, int w, int par,
    const u32 (&lov)[2][4], float (&cum)[2][4], int (&evti)[2][4],
    const floatx4 (&bank)[2], uint2 (*spair)[4])
{
    const float NEGINF = __uint_as_float(0xFF800000u);
    // ---- per-wave (v, lo) tournament: ascending-index order, strict >
    float v0 = cum[0][0]; u32 l0 = lov[0][0];
    vsel(v0, l0, cum[0][1], lov[0][1]);
    float v1 = cum[0][2]; u32 l1 = lov[0][2];
    vsel(v1, l1, cum[0][3], lov[0][3]);
    vsel(v0, l0, v1, l1);
    float v2 = cum[1][0]; u32 l2 = lov[1][0];
    vsel(v2, l2, cum[1][1], lov[1][1]);
    float v3 = cum[1][2]; u32 l3 = lov[1][2];
    vsel(v3, l3, cum[1][3], lov[1][3]);
    vsel(v2, l2, v3, l3);
    vsel(v0, l0, v2, l2);
    wave_argmax_to63(v0, l0);
    // ---- cross-wave exchange (double-buffered by parity)
    if (t == 63) spair[par][w] = make_uint2(l0, (u32)__float_as_int(v0));
    asm volatile("s_waitcnt lgkmcnt(0)" ::: "memory");
    __builtin_amdgcn_sched_barrier(0);
    __builtin_amdgcn_s_barrier();      // raw barrier: no vmcnt drain
    __builtin_amdgcn_sched_barrier(0);
    uint2 q0 = spair[par][0], q1 = spair[par][1];
    uint2 q2 = spair[par][2], q3 = spair[par][3];
    long long k0 = (long long)((((u64)q0.y) << 32) | q0.x);
    long long k1 = (long long)((((u64)q1.y) << 32) | q1.x);
    long long k2 = (long long)((((u64)q2.y) << 32) | q2.x);
    long long k3 = (long long)((((u64)q3.y) << 32) | q3.x);
    long long ba = k0 > k1 ? k0 : k1;
    long long bb = k2 > k3 ? k2 : k3;
    long long bst = ba > bb ? ba : bb;   // packs unique (lo distinct)
    const u32 lostar = (u32)(bst & 0xFFFFFFFFll);
    // ---- update: Fm[i] -> Fm[i+1]
#pragma unroll
    for (int c = 0; c < 2; ++c) {
        cum[c][0] += bank[c][0]; cum[c][1] += bank[c][1];
        cum[c][2] += bank[c][2]; cum[c][3] += bank[c][3];
    }
    // ---- poison + record: branch-free, lostar uniform
#pragma unroll
    for (int c = 0; c < 2; ++c)
#pragma unroll
        for (int e = 0; e < 4; ++e) {
            bool hit = (lov[c][e] == lostar);
            cum[c][e] = hit ? NEGINF : cum[c][e];
            evti[c][e] = hit ? i : evti[c][e];
        }
}

__device__ void evict_role(const float* __restrict__ S,
                           const float* __restrict__ P,
                           int* __restrict__ evt)
{
    int b = blockIdx.x;
    int tid = threadIdx.x;
    int w = tid >> 6, t = tid & 63;            // 4 waves
    const float* Sb = S + (size_t)b * N_ * M_;
    int* evtb = evt + b * M_;
    const int mbase = 512 * w + 4 * t;
    const u32 wbyte = (u32)(2048 * w + 16 * t);  // byte offset within a row
    __shared__ uint2 spair[2][4];               // [parity][wave]
    u32 lov[2][4];
    int evti[2][4];
#pragma unroll
    for (int c = 0; c < 2; ++c)
#pragma unroll
        for (int e = 0; e < 4; ++e) {
            lov[c][e] = (u32)(2048 - (mbase + 256 * c + e));
            evti[c][e] = 0x3FFFFFFF;
        }
    // initial cum = column sums of the 8 partial chunks (same per-slot add
    // order as rounds 0-13 -> bitwise identical trajectories)
    float cum[2][4];
#pragma unroll
    for (int c = 0; c < 2; ++c) {
        float ax = 0.f, ay = 0.f, az = 0.f, aw = 0.f;
#pragma unroll
        for (int cc = 0; cc < 8; ++cc) {
            floatx4 pv = *(const floatx4*)&P[((size_t)b * 8 + cc) * M_ + mbase + 256 * c];
            ax += pv[0]; ay += pv[1]; az += pv[2]; aw += pv[3];
        }
        cum[c][0] = ax; cum[c][1] = ay; cum[c][2] = az; cum[c][3] = aw;
    }
    // fence: drain compiler-tracked loads so asm vmcnt counting is exact
    VWAIT0();
    floatx4 bA[2], bB[2], bC[2], bD[2];
    ISSUE2(bA, 1024)
    ISSUE2(bB, 1025)
    ISSUE2(bC, 1026)
    ISSUE2(bD, 1027)
#pragma unroll 1
    for (int ip = 1024; ip < 2048; ip += 4) {
        VWAIT6();
        evict_step4(ip + 0, t, w, 0, lov, cum, evti, bA, spair);
        ISSUE2(bA, ip + 4)
        VWAIT6();
        evict_step4(ip + 1, t, w, 1, lov, cum, evti, bB, spair);
        ISSUE2(bB, ip + 5)
        VWAIT6();
        evict_step4(ip + 2, t, w, 0, lov, cum, evti, bC, spair);
        ISSUE2(bC, ip + 6)
        VWAIT6();
        evict_step4(ip + 3, t, w, 1, lov, cum, evti, bD, spair);
        ISSUE2(bD, ip + 7)
    }
    VWAIT0();   // drain leftover bank loads before reusing the vmem queue
    // single coalesced write pass (the only global stores in this role)
#pragma unroll
    for (int c = 0; c < 2; ++c) {
        int4 o; o.x = evti[c][0]; o.y = evti[c][1];
        o.z = evti[c][2]; o.w = evti[c][3];
        *(int4*)&evtb[mbase + 256 * c] = o;
    }
}

// ------------------------------------------------------ flash attention
// role shared by the fused launch (evtg==nullptr: q<1024, mask pure causal)
// and flash2 (evtg!=nullptr).
__device__ void flash_role(
    const u16* __restrict__ Qb, const u16* __restrict__ Kb,
    const u16* __restrict__ Vb, const int* __restrict__ evtg,
    u16* __restrict__ Ob, int bh, int q0, int ktiles)
{
    int b = bh >> 4, h = bh & 15;
    int tid = threadIdx.x, lane = tid & 63, w = tid >> 6;
    int quad = lane >> 4, l16 = lane & 15;
    const u16* Qh = Qb + (size_t)bh * N_ * DH_;
    const u16* Kh = Kb + (size_t)bh * N_ * DH_;
    const u16* Vh = Vb + (size_t)bh * N_ * DH_;
    __shared__ __align__(16) u16 sK[64 * 64];
    __shared__ __align__(16) u16 sV[64 * 64];     // transposed [dh][key]
    __shared__ __align__(16) u16 sP[4][16 * 64];  // wave-private P
    __shared__ int sevt[64];

    // Q A-frags in registers: A[m=lane&15][k=quad*8+j]
    short8 aq0 = *(const short8*)&Qh[(size_t)(q0 + w * 16 + l16) * 64 + quad * 8];
    short8 aq1 = *(const short8*)&Qh[(size_t)(q0 + w * 16 + l16) * 64 + quad * 8 + 32];

    floatx4 zero = {0.f, 0.f, 0.f, 0.f};
    floatx4 accO[4];
#pragma unroll
    for (int d = 0; d < 4; ++d) accO[d] = zero;
    float m_i[4] = {-1e30f, -1e30f, -1e30f, -1e30f};
    float l_i[4] = {0.f, 0.f, 0.f, 0.f};

    for (int kt = 0; kt < ktiles; ++kt) {
        int k0 = kt * 64;
#pragma unroll
        for (int it = 0; it < 2; ++it) {
            int e = (tid + it * 256) * 8;
            int r = e >> 6, c = e & 63;
            *(uint4*)&sK[e] = *(const uint4*)&Kh[(size_t)(k0 + r) * 64 + c];
            uint4 vv = *(const uint4*)&Vh[(size_t)(k0 + r) * 64 + c];
            sV[(c + 0) * 64 + r] = (u16)(vv.x & 0xFFFF);
            sV[(c + 1) * 64 + r] = (u16)(vv.x >> 16);
            sV[(c + 2) * 64 + r] = (u16)(vv.y & 0xFFFF);
            sV[(c + 3) * 64 + r] = (u16)(vv.y >> 16);
            sV[(c + 4) * 64 + r] = (u16)(vv.z & 0xFFFF);
            sV[(c + 5) * 64 + r] = (u16)(vv.z >> 16);
            sV[(c + 6) * 64 + r] = (u16)(vv.w & 0xFFFF);
            sV[(c + 7) * 64 + r] = (u16)(vv.w >> 16);
        }
        if (evtg && tid < 64) sevt[tid] = evtg[b * M_ + k0 + tid];
        __syncthreads();

        floatx4 lg[4];
        int nbase = q0 + w * 16 + quad * 4;
#pragma unroll
        for (int s = 0; s < 4; ++s) {
            floatx4 sc = zero;
            short8 bk0 = *(const short8*)&sK[(s * 16 + l16) * 64 + quad * 8];
            short8 bk1 = *(const short8*)&sK[(s * 16 + l16) * 64 + quad * 8 + 32];
            sc = __builtin_amdgcn_mfma_f32_16x16x32_bf16(aq0, bk0, sc, 0, 0, 0);
            sc = __builtin_amdgcn_mfma_f32_16x16x32_bf16(aq1, bk1, sc, 0, 0, 0);
            int m = k0 + s * 16 + l16;
            int ev = evtg ? sevt[s * 16 + l16] : 0x7FFFFFFF;
#pragma unroll
            for (int r = 0; r < 4; ++r) {
                int n = nbase + r;
                bool keep = (m <= n) && (n < ev);
                lg[s][r] = keep ? sc[r] * 0.125f : -1e30f;
            }
        }
        float mnew[4], scale[4], rs[4];
#pragma unroll
        for (int r = 0; r < 4; ++r) {
            float mx = fmaxf(fmaxf(lg[0][r], lg[1][r]), fmaxf(lg[2][r], lg[3][r]));
#pragma unroll
            for (int d = 1; d < 16; d <<= 1) mx = fmaxf(mx, __shfl_xor(mx, d));
            mnew[r] = fmaxf(m_i[r], mx);
            scale[r] = __expf(m_i[r] - mnew[r]);
            m_i[r] = mnew[r];
            rs[r] = 0.f;
        }
#pragma unroll
        for (int s = 0; s < 4; ++s)
#pragma unroll
            for (int r = 0; r < 4; ++r) {
                float p = __expf(lg[s][r] - mnew[r]);
                rs[r] += p;
                sP[w][(quad * 4 + r) * 64 + s * 16 + l16] = f2b(p);
            }
#pragma unroll
        for (int r = 0; r < 4; ++r) {
            float t_ = rs[r];
#pragma unroll
            for (int d = 1; d < 16; d <<= 1) t_ += __shfl_xor(t_, d);
            l_i[r] = l_i[r] * scale[r] + t_;
        }
#pragma unroll
        for (int dd = 0; dd < 4; ++dd) {
            accO[dd][0] *= scale[0]; accO[dd][1] *= scale[1];
            accO[dd][2] *= scale[2]; accO[dd][3] *= scale[3];
        }
        // P: C-layout -> A-layout via wave-private LDS round-trip
        short8 ap0 = *(const short8*)&sP[w][l16 * 64 + quad * 8];
        short8 ap1 = *(const short8*)&sP[w][l16 * 64 + quad * 8 + 32];
#pragma unroll
        for (int dd = 0; dd < 4; ++dd) {
            short8 bv0 = *(const short8*)&sV[(dd * 16 + l16) * 64 + quad * 8];
            short8 bv1 = *(const short8*)&sV[(dd * 16 + l16) * 64 + quad * 8 + 32];
            accO[dd] = __builtin_amdgcn_mfma_f32_16x16x32_bf16(ap0, bv0, accO[dd], 0, 0, 0);
            accO[dd] = __builtin_amdgcn_mfma_f32_16x16x32_bf16(ap1, bv1, accO[dd], 0, 0, 0);
        }
        __syncthreads();
    }
#pragma unroll
    for (int dd = 0; dd < 4; ++dd)
#pragma unroll
        for (int r = 0; r < 4; ++r) {
            int n = q0 + w * 16 + quad * 4 + r;
            int col = h * 64 + dd * 16 + l16;
            Ob[((size_t)b * N_ + n) * D_ + col] = f2b(accO[dd][r] / l_i[r]);
        }
}

// --------------------------- fused launch: evict ∥ flash part 1 (q<1024)
__global__ __launch_bounds__(256) void fused_evict_flash1(
    const float* __restrict__ S, const float* __restrict__ P,
    int* __restrict__ evt,
    const u16* __restrict__ Qb, const u16* __restrict__ Kb,
    const u16* __restrict__ Vb, u16* __restrict__ Ob)
{
    if (blockIdx.x < 2) {
        evict_role(S, P, evt);
    } else {
        int fid = blockIdx.x - 2;          // 0..511
        int bh = fid >> 4, j = fid & 15;   // q-tiles 0..15: n < 1024, no evt
        flash_role(Qb, Kb, Vb, nullptr, Ob, bh, j * 64, j + 1);
    }
}

// --------------------------------------- flash part 2 (q>=1024, needs evt)
__global__ __launch_bounds__(256) void flash2_kernel(
    const u16* __restrict__ Qb, const u16* __restrict__ Kb,
    const u16* __restrict__ Vb, const int* __restrict__ evt,
    u16* __restrict__ Ob)
{
    int j = blockIdx.x + 16;               // q-tiles 16..31
    flash_role(Qb, Kb, Vb, evt, Ob, blockIdx.y, j * 64, j + 1);
}

// ---------------------------------------------------------------- launch
extern "C" void kernel_launch(void* const* d_in, const int* in_sizes, int n_in,
                              void* d_out, int out_size, void* d_ws, size_t ws_size,
                              hipStream_t stream)
{
    (void)in_sizes; (void)n_in; (void)out_size; (void)ws_size;
    const float* X  = (const float*)d_in[0];
    const float* Wq = (const float*)d_in[1];
    const float* Wk = (const float*)d_in[2];
    const float* Wv = (const float*)d_in[3];
    const float* Wo = (const float*)d_in[4];
    const float* gq = (const float*)d_in[5];
    const float* bq = (const float*)d_in[6];
    const float* gk = (const float*)d_in[7];
    const float* bk = (const float*)d_in[8];
    // d_in[9] cache_k, d_in[10] cache_v, d_in[11] start_pos: start_pos==0 here.

    char* p = (char*)d_ws;
    const size_t SZ_XH = (size_t)ROWS_ * D_ * 2;   // 8 MiB bf16
    const size_t SZ_W  = (size_t)D_ * D_ * 2;      // 2 MiB bf16
    const size_t SZ_Y  = (size_t)ROWS_ * D_ * 4;   // 16 MiB fp32
    const size_t SZ_PK = (size_t)ROWS_ * D_ * 2;   // 8 MiB bf16
    const size_t SZ_H0 = (size_t)ROWS_ * 64 * 4;   // 1 MiB fp32

    size_t o = 0;
    u16* Xhi = (u16*)(p + o); o += SZ_XH;
    u16* Xlo = (u16*)(p + o); o += SZ_XH;
    u16* Wqh = (u16*)(p + o); o += SZ_W;
    u16* Wql = (u16*)(p + o); o += SZ_W;
    u16* Wkh = (u16*)(p + o); o += SZ_W;
    u16* Wkl = (u16*)(p + o); o += SZ_W;
    u16* Wvh = (u16*)(p + o); o += SZ_W;
    u16* Woh = (u16*)(p + o); o += SZ_W;
    float* Yq = (float*)(p + o); size_t oYq = o; o += SZ_Y;
    float* Yk = (float*)(p + o); o += SZ_Y;
    float* Yv = (float*)(p + o); o += SZ_Y;     // unused (Vb fused); kept for layout stability
    u16* Qb = (u16*)(p + o); o += SZ_PK;
    u16* Kb = (u16*)(p + o); o += SZ_PK;
    u16* Vb = (u16*)(p + o); o += SZ_PK;
    float* q0s = (float*)(p + o); o += SZ_H0;
    float* k0s = (float*)(p + o); o += SZ_H0;
    float* Pp  = (float*)(p + o); o += (size_t)B_ * 8 * M_ * 4;
    int* evt   = (int*)(p + o);  o += (size_t)B_ * M_ * 4;
    (void)Yv;
    // overlays (dead slots):
    float* S = (float*)(p + oYq);   // 32 MiB over Yq+Yk, used after LN
    u16* Ob  = Xhi;                 // 8 MiB over Xhi, used after all X-GEMMs

    cast_x_kernel<<<ROWS_ * D_ / (256 * 4), 256, 0, stream>>>(X, Xhi, Xlo);
    cast_w_all_kernel<<<dim3(32, 32, 4), dim3(32, 32), 0, stream>>>(
        Wq, Wk, Wv, Wo, Wqh, Wql, Wkh, Wkl, Wvh, Woh);

    dim3 ggrid(D_ / 128, ROWS_ / 128);
    gemm_kernel<<<ggrid, 256, 0, stream>>>(Xhi, Xlo, Wqh, Wql, 1, Yq, nullptr);
    gemm_kernel<<<ggrid, 256, 0, stream>>>(Xhi, Xlo, Wkh, Wkl, 1, Yk, nullptr);
    gemm_kernel<<<ggrid, 256, 0, stream>>>(Xhi, nullptr, Wvh, nullptr, 0, nullptr, Vb);

    lnpack_kernel<<<ROWS_, 256, 0, stream>>>(Yq, gq, bq, Qb, q0s);
    lnpack_kernel<<<ROWS_, 256, 0, stream>>>(Yk, gk, bk, Kb, k0s);

    s_kernel<<<dim3(M_ / 16, N_ / 16, B_), dim3(16, 16), 0, stream>>>(q0s, k0s, S);
    p_kernel<<<dim3(M_ / 256, 8, B_), 256, 0, stream>>>(S, Pp);

    // evict (blocks 0,1) runs concurrently with flash q<1024 (blocks 2..513)
    fused_evict_flash1<<<514, 256, 0, stream>>>(S, Pp, evt, Qb, Kb, Vb, Ob);
    flash2_kernel<<<dim3(16, B_ * H_), 256, 0, stream>>>(Qb, Kb, Vb, evt, Ob);

    gemm_kernel<<<ggrid, 256, 0, stream>>>(Ob, nullptr, Woh, nullptr, 0, (float*)d_out, nullptr);
}

// Round 15
// 812.644 us; speedup vs baseline: 1.0702x; 1.0702x over previous
//
// MultiheadSelectiveAttentionWithTokenPruning — MI355X round 15
// (r10 proven base. r13 swizzle and r14 fusions both regressed — reverted.
//  Two new changes: 64x64-tile s_kernel (bit-identical, 16x fewer blocks);
//  flash2 ∥ gemmO-part1 overlap (Ob rows n<1024 final after fused launch).)
//
// Pipeline (all on `stream`, graph-capture safe, no statics):
//  1  cast_x      : X fp32 -> Xhi/Xlo bf16 (split for bf16x3 GEMM)
//  2  cast_w x4   : W fp32 -> W^T bf16 (hi[+lo for Wq/Wk])
//  3  gemm split  : Yq = X@Wq  (hi*hi + hi*lo + lo*hi)  ~fp32 accuracy
//  4  gemm split  : Yk = X@Wk
//  5  gemm        : Yv = X@Wv  (plain bf16)
//  6  lnpack      : LN(Yq) -> Qb bf16 + q0s fp32 (head-0 selection)
//  7  lnpack      : LN(Yk) -> Kb + k0s
//  8  lnpack      : Yv -> Vb (cast only)
//  9  s64_kernel  : S[b,n,m] = relu(q0s.k0s/8), 64x64 tiles (2048 blocks vs
//                   32768; same d-ascending FMA order -> bit-identical S)
// 10  p_kernel    : column partial sums of S rows 0..1023 (8 chunks)
// 11  FUSED       : evict (2 blocks, r9-proven 4-wave code) ∥ flash part 1
//                   (512 blocks, q<1024: prune mask vacuous). ~365 µs.
// 12  FUSED       : flash2 (q>=1024, needs evt; 512 blocks) ∥ gemmO part 1
//                   (row-blocks y in {0..7,16..23}: Ob rows n<1024, final
//                   after launch 11; 128 blocks). Disjoint data, no deps.
// 13  gemmO part2 : row-blocks y in {8..15,24..31} (needs flash2's Ob rows).
//
// ws overlays: Ob reuses Xhi slot (dead after step 5); S reuses Yq+Yk slots
// (dead after steps 6/7). Peak ws ~107.1 MB.

#include <hip/hip_runtime.h>

#define B_    2
#define N_    2048
#define D_    1024
#define H_    16
#define DH_   64
#define M_    2048
#define ROWS_ 4096
#define BUD_  1024

typedef unsigned short u16;
typedef unsigned int   u32;
typedef unsigned long long u64;
typedef __attribute__((ext_vector_type(8))) short short8;
typedef __attribute__((ext_vector_type(4))) float floatx4;

__device__ __forceinline__ u16 f2b(float f) {
    u32 u = __float_as_uint(f);
    return (u16)((u + 0x7FFFu + ((u >> 16) & 1u)) >> 16);   // RNE
}
__device__ __forceinline__ float b2f(u16 h) {
    return __uint_as_float(((u32)h) << 16);
}

// ---------------------------------------------------------------- cast X
__global__ __launch_bounds__(256) void cast_x_kernel(
    const float* __restrict__ X, u16* __restrict__ Xhi, u16* __restrict__ Xlo)
{
    int idx = (blockIdx.x * 256 + threadIdx.x) * 4;
    float4 v = *(const float4*)&X[idx];
    u16 h0 = f2b(v.x), h1 = f2b(v.y), h2 = f2b(v.z), h3 = f2b(v.w);
    ushort4 hv; hv.x = h0; hv.y = h1; hv.z = h2; hv.w = h3;
    *(ushort4*)&Xhi[idx] = hv;
    ushort4 lv;
    lv.x = f2b(v.x - b2f(h0)); lv.y = f2b(v.y - b2f(h1));
    lv.z = f2b(v.z - b2f(h2)); lv.w = f2b(v.w - b2f(h3));
    *(ushort4*)&Xlo[idx] = lv;
}

// ------------------------------------------------- cast + transpose W
__global__ __launch_bounds__(1024) void cast_w_kernel(
    const float* __restrict__ W, u16* __restrict__ Whi, u16* __restrict__ Wlo,
    int do_lo)
{
    __shared__ float tile[32][33];
    int tx = threadIdx.x, ty = threadIdx.y;
    int x = blockIdx.x * 32 + tx, y = blockIdx.y * 32 + ty;
    tile[ty][tx] = W[(size_t)y * D_ + x];
    __syncthreads();
    float v = tile[tx][ty];
    int n = blockIdx.x * 32 + ty, k = blockIdx.y * 32 + tx;
    u16 h = f2b(v);
    Whi[(size_t)n * D_ + k] = h;
    if (do_lo) Wlo[(size_t)n * D_ + k] = f2b(v - b2f(h));
}

// ------------------------------------------------------------- GEMM core
// C[row][col] = A[4096][1024] @ Bt^T  (Bt stored [n][k]); tile 128x128.
// MODE 1: C = Ah*Bh + Ah*Bl + Al*Bh  (bf16x3 split, ~fp32 precision)
template<int MODE>
__device__ void gemm_core(
    const u16* __restrict__ Ah, const u16* __restrict__ Al,
    const u16* __restrict__ Bh, const u16* __restrict__ Bl,
    float* __restrict__ C, int bx, int m0)
{
    __shared__ __align__(16) u16 sAh[128 * 32];
    __shared__ __align__(16) u16 sBh[128 * 32];
    __shared__ __align__(16) u16 sAl[MODE ? 128 * 32 : 8];
    __shared__ __align__(16) u16 sBl[MODE ? 128 * 32 : 8];
    int tid = threadIdx.x;
    int lane = tid & 63, wv = tid >> 6;
    int wr = wv >> 1, wc = wv & 1;
    int quad = lane >> 4, l16 = lane & 15;
    int n0 = bx * 128;

    floatx4 acc[4][4];
    floatx4 zero = {0.f, 0.f, 0.f, 0.f};
#pragma unroll
    for (int i = 0; i < 4; ++i)
#pragma unroll
        for (int j = 0; j < 4; ++j) acc[i][j] = zero;

    for (int k0 = 0; k0 < 1024; k0 += 32) {
#pragma unroll
        for (int it = 0; it < 2; ++it) {
            int e = (tid + it * 256) * 8;
            int r = e >> 5, c = e & 31;
            *(uint4*)&sAh[e] = *(const uint4*)&Ah[(size_t)(m0 + r) * 1024 + k0 + c];
            *(uint4*)&sBh[e] = *(const uint4*)&Bh[(size_t)(n0 + r) * 1024 + k0 + c];
            if (MODE) {
                *(uint4*)&sAl[e] = *(const uint4*)&Al[(size_t)(m0 + r) * 1024 + k0 + c];
                *(uint4*)&sBl[e] = *(const uint4*)&Bl[(size_t)(n0 + r) * 1024 + k0 + c];
            }
        }
        __syncthreads();
        short8 ah[4], al[4], bh[4], bl[4];
#pragma unroll
        for (int x = 0; x < 4; ++x) {
            int ra = (wr * 64 + x * 16 + l16) * 32 + quad * 8;
            int rb = (wc * 64 + x * 16 + l16) * 32 + quad * 8;
            ah[x] = *(const short8*)&sAh[ra];
            bh[x] = *(const short8*)&sBh[rb];
            if (MODE) {
                al[x] = *(const short8*)&sAl[ra];
                bl[x] = *(const short8*)&sBl[rb];
            }
        }
#pragma unroll
        for (int mi = 0; mi < 4; ++mi)
#pragma unroll
            for (int ni = 0; ni < 4; ++ni) {
                acc[mi][ni] = __builtin_amdgcn_mfma_f32_16x16x32_bf16(
                    ah[mi], bh[ni], acc[mi][ni], 0, 0, 0);
                if (MODE) {
                    acc[mi][ni] = __builtin_amdgcn_mfma_f32_16x16x32_bf16(
                        ah[mi], bl[ni], acc[mi][ni], 0, 0, 0);
                    acc[mi][ni] = __builtin_amdgcn_mfma_f32_16x16x32_bf16(
                        al[mi], bh[ni], acc[mi][ni], 0, 0, 0);
                }
            }
        __syncthreads();
    }
    // C/D layout: col = lane&15, row = (lane>>4)*4 + reg   [verified m89/m91]
#pragma unroll
    for (int mi = 0; mi < 4; ++mi)
#pragma unroll
        for (int ni = 0; ni < 4; ++ni)
#pragma unroll
            for (int r = 0; r < 4; ++r) {
                int row = m0 + wr * 64 + mi * 16 + quad * 4 + r;
                int col = n0 + wc * 64 + ni * 16 + l16;
                C[(size_t)row * 1024 + col] = acc[mi][ni][r];
            }
}

// standalone gemm launches. ymode 0: m0 = blockIdx.y*128 (grid y=32)
// ymode 2: part-2 rows, y'<8 -> y'+8, else y'+16 (grid y=16)
template<int MODE>
__global__ __launch_bounds__(256) void gemm_kernel_t(
    const u16* __restrict__ Ah, const u16* __restrict__ Al,
    const u16* __restrict__ Bh, const u16* __restrict__ Bl,
    float* __restrict__ C, int ymode)
{
    int by = blockIdx.y;
    int yidx = (ymode == 0) ? by : ((by < 8) ? by + 8 : by + 16);
    gemm_core<MODE>(Ah, Al, Bh, Bl, C, blockIdx.x, yidx * 128);
}

// ----------------------------------------------------- LayerNorm + pack
__global__ __launch_bounds__(256) void lnpack_kernel(
    const float* __restrict__ Y, const float* __restrict__ gamma,
    const float* __restrict__ beta, u16* __restrict__ Pk,
    float* __restrict__ head0, int do_ln)
{
    int r = blockIdx.x;
    int tid = threadIdx.x;
    float4 v = *(const float4*)&Y[(size_t)r * D_ + tid * 4];
    float mu = 0.f, rsig = 1.f;
    __shared__ float sS[4], sQ[4];
    if (do_ln) {
        float s = v.x + v.y + v.z + v.w;
        float q = v.x * v.x + v.y * v.y + v.z * v.z + v.w * v.w;
#pragma unroll
        for (int d = 1; d < 64; d <<= 1) { s += __shfl_xor(s, d); q += __shfl_xor(q, d); }
        if ((tid & 63) == 0) { sS[tid >> 6] = s; sQ[tid >> 6] = q; }
        __syncthreads();
        s = sS[0] + sS[1] + sS[2] + sS[3];
        q = sQ[0] + sQ[1] + sQ[2] + sQ[3];
        mu = s * (1.f / 1024.f);
        float var = q * (1.f / 1024.f) - mu * mu;
        rsig = rsqrtf(var + 1e-5f);
    }
    int b = r >> 11, n = r & 2047;
    float xs[4] = {v.x, v.y, v.z, v.w};
#pragma unroll
    for (int j = 0; j < 4; ++j) {
        int c = tid * 4 + j;
        float val = do_ln ? ((xs[j] - mu) * rsig * gamma[c] + beta[c]) : xs[j];
        int h = c >> 6, dh = c & 63;
        Pk[(((size_t)b * H_ + h) * N_ + n) * DH_ + dh] = f2b(val);
        if (head0 && c < 64) head0[(size_t)r * 64 + c] = val;
    }
}

// ------------------------------------- head-0 selection scores S (64x64)
// Bit-identical to the 16x16 version: each output's dot product runs
// d = 0..63 ascending in a single fp32 FMA chain.
__global__ __launch_bounds__(256) void s64_kernel(
    const float* __restrict__ q0, const float* __restrict__ k0,
    float* __restrict__ S)
{
    int b = blockIdx.z;
    int n0 = blockIdx.y * 64, m0 = blockIdx.x * 64;
    int tid = threadIdx.x;
    int tx = tid & 15, ty = tid >> 4;
    floatx4 zero = {0.f, 0.f, 0.f, 0.f};
    if (m0 > n0 + 63) {                 // fully above diagonal -> zeros
#pragma unroll
        for (int i = 0; i < 4; ++i) {
            int n = n0 + 4 * ty + i;
            *(floatx4*)&S[((size_t)b * N_ + n) * M_ + m0 + 4 * tx] = zero;
        }
        return;
    }
    __shared__ float sq[64][65], sk[64][65];
    {
        int r = tid >> 2, cseg = (tid & 3) * 16;
        const float* qrow = &q0[((size_t)b * N_ + n0 + r) * 64 + cseg];
        const float* krow = &k0[((size_t)b * N_ + m0 + r) * 64 + cseg];
#pragma unroll
        for (int u = 0; u < 4; ++u) {
            float4 qa = *(const float4*)&qrow[u * 4];
            sq[r][cseg + u * 4 + 0] = qa.x; sq[r][cseg + u * 4 + 1] = qa.y;
            sq[r][cseg + u * 4 + 2] = qa.z; sq[r][cseg + u * 4 + 3] = qa.w;
            float4 ka = *(const float4*)&krow[u * 4];
            sk[r][cseg + u * 4 + 0] = ka.x; sk[r][cseg + u * 4 + 1] = ka.y;
            sk[r][cseg + u * 4 + 2] = ka.z; sk[r][cseg + u * 4 + 3] = ka.w;
        }
    }
    __syncthreads();
    float acc[4][4];
#pragma unroll
    for (int i = 0; i < 4; ++i)
#pragma unroll
        for (int j = 0; j < 4; ++j) acc[i][j] = 0.f;
#pragma unroll 8
    for (int d = 0; d < 64; ++d) {
        float qv[4], kv[4];
#pragma unroll
        for (int i = 0; i < 4; ++i) qv[i] = sq[4 * ty + i][d];
#pragma unroll
        for (int j = 0; j < 4; ++j) kv[j] = sk[4 * tx + j][d];
#pragma unroll
        for (int i = 0; i < 4; ++i)
#pragma unroll
            for (int j = 0; j < 4; ++j) acc[i][j] += qv[i] * kv[j];
    }
#pragma unroll
    for (int i = 0; i < 4; ++i) {
        int n = n0 + 4 * ty + i;
        floatx4 out;
#pragma unroll
        for (int j = 0; j < 4; ++j) {
            int m = m0 + 4 * tx + j;
            // causal m>n -> 0 ; diagonal m==n -> 0 ; col 0 -> 0
            out[j] = (m < n && m != 0) ? fmaxf(acc[i][j] * 0.125f, 0.f) : 0.f;
        }
        *(floatx4*)&S[((size_t)b * N_ + n) * M_ + m0 + 4 * tx] = out;
    }
}

// -------------------------------- partial column sums of S rows 0..1023
__global__ __launch_bounds__(256) void p_kernel(const float* __restrict__ S,
                                                float* __restrict__ P)
{
    int b = blockIdx.z, c = blockIdx.y;
    int m = blockIdx.x * 256 + threadIdx.x;
    const float* base = S + ((size_t)b * N_ + c * 128) * M_ + m;
    float s = 0.f;
    for (int j = 0; j < 128; ++j) s += base[(size_t)j * M_];
    P[((size_t)b * 8 + c) * M_ + m] = s;
}

// --------------------------------------------- sequential greedy eviction
// (r9-proven 4-wave code, byte-identical logic)
__device__ __forceinline__ void vsel(float& va, u32& la, float vb, u32 lb) {
    bool tk = vb > va;
    va = tk ? vb : va;
    la = tk ? lb : la;
}

template<int CTRL, int RMASK>
__device__ __forceinline__ void dpp_max_pack(float& v, u32& lo) {
    int hi = __float_as_int(v);
    int hi_o = __builtin_amdgcn_update_dpp(hi, hi, CTRL, RMASK, 0xF, false);
    int lo_o = __builtin_amdgcn_update_dpp((int)lo, (int)lo, CTRL, RMASK, 0xF, false);
    long long a = (long long)((((u64)(u32)hi) << 32) | lo);
    long long b = (long long)((((u64)(u32)hi_o) << 32) | (u32)lo_o);
    bool tk = b > a;
    v = tk ? __int_as_float(hi_o) : v;
    lo = tk ? (u32)lo_o : lo;
}

__device__ __forceinline__ void wave_argmax_to63(float& v, u32& lo) {
    dpp_max_pack<0x121, 0xF>(v, lo);   // row_ror:1
    dpp_max_pack<0x122, 0xF>(v, lo);   // row_ror:2
    dpp_max_pack<0x124, 0xF>(v, lo);   // row_ror:4
    dpp_max_pack<0x128, 0xF>(v, lo);   // row_ror:8
    dpp_max_pack<0x142, 0xA>(v, lo);   // row_bcast15 -> rows 1,3
    dpp_max_pack<0x143, 0xC>(v, lo);   // row_bcast31 -> rows 2,3
}

#define GLOAD(dst, voff, ptr, imm)                                    \
    asm volatile("global_load_dwordx4 %0, %1, %2 offset:" #imm        \
                 : "=v"(dst) : "v"(voff), "s"(ptr) : "memory")

#define ISSUE2(bank, row)                                             \
    {                                                                 \
        u32 r_ = (u32)((row) < 2047 ? (row) : 2047);                  \
        u32 vo = wbyte + r_ * 8192u;                                  \
        GLOAD(bank[0], vo, Sb, 0);                                    \
        GLOAD(bank[1], vo, Sb, 1024);                                 \
    }

#define VWAIT6()                                                      \
    do { asm volatile("s_waitcnt vmcnt(6)" ::: "memory");             \
         __builtin_amdgcn_sched_barrier(0); } while (0)
#define VWAIT0()                                                      \
    do { asm volatile("s_waitcnt vmcnt(0)" ::: "memory");             \
         __builtin_amdgcn_sched_barrier(0); } while (0)

__device__ __forceinline__ void evict_step4(
    int i, int t, int w, int par,
    const u32 (&lov)[2][4], float (&cum)[2][4], int (&evti)[2][4],
    const floatx4 (&bank)[2], uint2 (*spair)[4])
{
    const float NEGINF = __uint_as_float(0xFF800000u);
    // ---- per-wave (v, lo) tournament: ascending-index order, strict >
    float v0 = cum[0][0]; u32 l0 = lov[0][0];
    vsel(v0, l0, cum[0][1], lov[0][1]);
    float v1 = cum[0][2]; u32 l1 = lov[0][2];
    vsel(v1, l1, cum[0][3], lov[0][3]);
    vsel(v0, l0, v1, l1);
    float v2 = cum[1][0]; u32 l2 = lov[1][0];
    vsel(v2, l2, cum[1][1], lov[1][1]);
    float v3 = cum[1][2]; u32 l3 = lov[1][2];
    vsel(v3, l3, cum[1][3], lov[1][3]);
    vsel(v2, l2, v3, l3);
    vsel(v0, l0, v2, l2);
    wave_argmax_to63(v0, l0);
    // ---- cross-wave exchange (double-buffered by parity)
    if (t == 63) spair[par][w] = make_uint2(l0, (u32)__float_as_int(v0));
    asm volatile("s_waitcnt lgkmcnt(0)" ::: "memory");
    __builtin_amdgcn_sched_barrier(0);
    __builtin_amdgcn_s_barrier();      // raw barrier: no vmcnt drain
    __builtin_amdgcn_sched_barrier(0);
    uint2 q0 = spair[par][0], q1 = spair[par][1];
    uint2 q2 = spair[par][2], q3 = spair[par][3];
    long long k0 = (long long)((((u64)q0.y) << 32) | q0.x);
    long long k1 = (long long)((((u64)q1.y) << 32) | q1.x);
    long long k2 = (long long)((((u64)q2.y) << 32) | q2.x);
    long long k3 = (long long)((((u64)q3.y) << 32) | q3.x);
    long long ba = k0 > k1 ? k0 : k1;
    long long bb = k2 > k3 ? k2 : k3;
    long long bst = ba > bb ? ba : bb;   // packs unique (lo distinct)
    const u32 lostar = (u32)(bst & 0xFFFFFFFFll);
    // ---- update: Fm[i] -> Fm[i+1]
#pragma unroll
    for (int c = 0; c < 2; ++c) {
        cum[c][0] += bank[c][0]; cum[c][1] += bank[c][1];
        cum[c][2] += bank[c][2]; cum[c][3] += bank[c][3];
    }
    // ---- poison + record: branch-free, lostar uniform
#pragma unroll
    for (int c = 0; c < 2; ++c)
#pragma unroll
        for (int e = 0; e < 4; ++e) {
            bool hit = (lov[c][e] == lostar);
            cum[c][e] = hit ? NEGINF : cum[c][e];
            evti[c][e] = hit ? i : evti[c][e];
        }
}

__device__ void evict_role(const float* __restrict__ S,
                           const float* __restrict__ P,
                           int* __restrict__ evt)
{
    int b = blockIdx.x;
    int tid = threadIdx.x;
    int w = tid >> 6, t = tid & 63;            // 4 waves
    const float* Sb = S + (size_t)b * N_ * M_;
    int* evtb = evt + b * M_;
    const int mbase = 512 * w + 4 * t;
    const u32 wbyte = (u32)(2048 * w + 16 * t);  // byte offset within a row
    __shared__ uint2 spair[2][4];               // [parity][wave]
    u32 lov[2][4];
    int evti[2][4];
#pragma unroll
    for (int c = 0; c < 2; ++c)
#pragma unroll
        for (int e = 0; e < 4; ++e) {
            lov[c][e] = (u32)(2048 - (mbase + 256 * c + e));
            evti[c][e] = 0x3FFFFFFF;
        }
    // initial cum = column sums of the 8 partial chunks (same per-slot add
    // order as rounds 0-14 -> bitwise identical trajectories)
    float cum[2][4];
#pragma unroll
    for (int c = 0; c < 2; ++c) {
        float ax = 0.f, ay = 0.f, az = 0.f, aw = 0.f;
#pragma unroll
        for (int cc = 0; cc < 8; ++cc) {
            floatx4 pv = *(const floatx4*)&P[((size_t)b * 8 + cc) * M_ + mbase + 256 * c];
            ax += pv[0]; ay += pv[1]; az += pv[2]; aw += pv[3];
        }
        cum[c][0] = ax; cum[c][1] = ay; cum[c][2] = az; cum[c][3] = aw;
    }
    // fence: drain compiler-tracked loads so asm vmcnt counting is exact
    VWAIT0();
    floatx4 bA[2], bB[2], bC[2], bD[2];
    ISSUE2(bA, 1024)
    ISSUE2(bB, 1025)
    ISSUE2(bC, 1026)
    ISSUE2(bD, 1027)
#pragma unroll 1
    for (int ip = 1024; ip < 2048; ip += 4) {
        VWAIT6();
        evict_step4(ip + 0, t, w, 0, lov, cum, evti, bA, spair);
        ISSUE2(bA, ip + 4)
        VWAIT6();
        evict_step4(ip + 1, t, w, 1, lov, cum, evti, bB, spair);
        ISSUE2(bB, ip + 5)
        VWAIT6();
        evict_step4(ip + 2, t, w, 0, lov, cum, evti, bC, spair);
        ISSUE2(bC, ip + 6)
        VWAIT6();
        evict_step4(ip + 3, t, w, 1, lov, cum, evti, bD, spair);
        ISSUE2(bD, ip + 7)
    }
    VWAIT0();   // drain leftover bank loads before reusing the vmem queue
    // single coalesced write pass (the only global stores in this role)
#pragma unroll
    for (int c = 0; c < 2; ++c) {
        int4 o; o.x = evti[c][0]; o.y = evti[c][1];
        o.z = evti[c][2]; o.w = evti[c][3];
        *(int4*)&evtb[mbase + 256 * c] = o;
    }
}

// ------------------------------------------------------ flash attention
// role shared by fused launches (evtg==nullptr: q<1024, mask pure causal).
__device__ void flash_role(
    const u16* __restrict__ Qb, const u16* __restrict__ Kb,
    const u16* __restrict__ Vb, const int* __restrict__ evtg,
    u16* __restrict__ Ob, int bh, int q0, int ktiles)
{
    int b = bh >> 4, h = bh & 15;
    int tid = threadIdx.x, lane = tid & 63, w = tid >> 6;
    int quad = lane >> 4, l16 = lane & 15;
    const u16* Qh = Qb + (size_t)bh * N_ * DH_;
    const u16* Kh = Kb + (size_t)bh * N_ * DH_;
    const u16* Vh = Vb + (size_t)bh * N_ * DH_;
    __shared__ __align__(16) u16 sK[64 * 64];
    __shared__ __align__(16) u16 sV[64 * 64];     // transposed [dh][key]
    __shared__ __align__(16) u16 sP[4][16 * 64];  // wave-private P
    __shared__ int sevt[64];

    // Q A-frags in registers: A[m=lane&15][k=quad*8+j]
    short8 aq0 = *(const short8*)&Qh[(size_t)(q0 + w * 16 + l16) * 64 + quad * 8];
    short8 aq1 = *(const short8*)&Qh[(size_t)(q0 + w * 16 + l16) * 64 + quad * 8 + 32];

    floatx4 zero = {0.f, 0.f, 0.f, 0.f};
    floatx4 accO[4];
#pragma unroll
    for (int d = 0; d < 4; ++d) accO[d] = zero;
    float m_i[4] = {-1e30f, -1e30f, -1e30f, -1e30f};
    float l_i[4] = {0.f, 0.f, 0.f, 0.f};

    for (int kt = 0; kt < ktiles; ++kt) {
        int k0 = kt * 64;
#pragma unroll
        for (int it = 0; it < 2; ++it) {
            int e = (tid + it * 256) * 8;
            int r = e >> 6, c = e & 63;
            *(uint4*)&sK[e] = *(const uint4*)&Kh[(size_t)(k0 + r) * 64 + c];
            uint4 vv = *(const uint4*)&Vh[(size_t)(k0 + r) * 64 + c];
            sV[(c + 0) * 64 + r] = (u16)(vv.x & 0xFFFF);
            sV[(c + 1) * 64 + r] = (u16)(vv.x >> 16);
            sV[(c + 2) * 64 + r] = (u16)(vv.y & 0xFFFF);
            sV[(c + 3) * 64 + r] = (u16)(vv.y >> 16);
            sV[(c + 4) * 64 + r] = (u16)(vv.z & 0xFFFF);
            sV[(c + 5) * 64 + r] = (u16)(vv.z >> 16);
            sV[(c + 6) * 64 + r] = (u16)(vv.w & 0xFFFF);
            sV[(c + 7) * 64 + r] = (u16)(vv.w >> 16);
        }
        if (evtg && tid < 64) sevt[tid] = evtg[b * M_ + k0 + tid];
        __syncthreads();

        floatx4 lg[4];
        int nbase = q0 + w * 16 + quad * 4;
#pragma unroll
        for (int s = 0; s < 4; ++s) {
            floatx4 sc = zero;
            short8 bk0 = *(const short8*)&sK[(s * 16 + l16) * 64 + quad * 8];
            short8 bk1 = *(const short8*)&sK[(s * 16 + l16) * 64 + quad * 8 + 32];
            sc = __builtin_amdgcn_mfma_f32_16x16x32_bf16(aq0, bk0, sc, 0, 0, 0);
            sc = __builtin_amdgcn_mfma_f32_16x16x32_bf16(aq1, bk1, sc, 0, 0, 0);
            int m = k0 + s * 16 + l16;
            int ev = evtg ? sevt[s * 16 + l16] : 0x7FFFFFFF;
#pragma unroll
            for (int r = 0; r < 4; ++r) {
                int n = nbase + r;
                bool keep = (m <= n) && (n < ev);
                lg[s][r] = keep ? sc[r] * 0.125f : -1e30f;
            }
        }
        float mnew[4], scale[4], rs[4];
#pragma unroll
        for (int r = 0; r < 4; ++r) {
            float mx = fmaxf(fmaxf(lg[0][r], lg[1][r]), fmaxf(lg[2][r], lg[3][r]));
#pragma unroll
            for (int d = 1; d < 16; d <<= 1) mx = fmaxf(mx, __shfl_xor(mx, d));
            mnew[r] = fmaxf(m_i[r], mx);
            scale[r] = __expf(m_i[r] - mnew[r]);
            m_i[r] = mnew[r];
            rs[r] = 0.f;
        }
#pragma unroll
        for (int s = 0; s < 4; ++s)
#pragma unroll
            for (int r = 0; r < 4; ++r) {
                float p = __expf(lg[s][r] - mnew[r]);
                rs[r] += p;
                sP[w][(quad * 4 + r) * 64 + s * 16 + l16] = f2b(p);
            }
#pragma unroll
        for (int r = 0; r < 4; ++r) {
            float t_ = rs[r];
#pragma unroll
            for (int d = 1; d < 16; d <<= 1) t_ += __shfl_xor(t_, d);
            l_i[r] = l_i[r] * scale[r] + t_;
        }
#pragma unroll
        for (int dd = 0; dd < 4; ++dd) {
            accO[dd][0] *= scale[0]; accO[dd][1] *= scale[1];
            accO[dd][2] *= scale[2]; accO[dd][3] *= scale[3];
        }
        // P: C-layout -> A-layout via wave-private LDS round-trip
        short8 ap0 = *(const short8*)&sP[w][l16 * 64 + quad * 8];
        short8 ap1 = *(const short8*)&sP[w][l16 * 64 + quad * 8 + 32];
#pragma unroll
        for (int dd = 0; dd < 4; ++dd) {
            short8 bv0 = *(const short8*)&sV[(dd * 16 + l16) * 64 + quad * 8];
            short8 bv1 = *(const short8*)&sV[(dd * 16 + l16) * 64 + quad * 8 + 32];
            accO[dd] = __builtin_amdgcn_mfma_f32_16x16x32_bf16(ap0, bv0, accO[dd], 0, 0, 0);
            accO[dd] = __builtin_amdgcn_mfma_f32_16x16x32_bf16(ap1, bv1, accO[dd], 0, 0, 0);
        }
        __syncthreads();
    }
#pragma unroll
    for (int dd = 0; dd < 4; ++dd)
#pragma unroll
        for (int r = 0; r < 4; ++r) {
            int n = q0 + w * 16 + quad * 4 + r;
            int col = h * 64 + dd * 16 + l16;
            Ob[((size_t)b * N_ + n) * D_ + col] = f2b(accO[dd][r] / l_i[r]);
        }
}

// --------------------------- fused launch: evict ∥ flash part 1 (q<1024)
__global__ __launch_bounds__(256) void fused_evict_flash1(
    const float* __restrict__ S, const float* __restrict__ P,
    int* __restrict__ evt,
    const u16* __restrict__ Qb, const u16* __restrict__ Kb,
    const u16* __restrict__ Vb, u16* __restrict__ Ob)
{
    if (blockIdx.x < 2) {
        evict_role(S, P, evt);
    } else {
        int fid = blockIdx.x - 2;          // 0..511
        int bh = fid >> 4, j = fid & 15;   // q-tiles 0..15: n < 1024, no evt
        flash_role(Qb, Kb, Vb, nullptr, Ob, bh, j * 64, j + 1);
    }
}

// ---------------- fused launch: flash part 2 (q>=1024) ∥ gemmO part 1
// gemmO part 1 covers row-blocks y in {0..7, 16..23} = Ob rows n<1024,
// which are complete after fused_evict_flash1. Disjoint from flash2's
// writes (Ob rows n>=1024) -> no dependency, any dispatch order safe.
__global__ __launch_bounds__(256) void fused_flash2_gemmo1(
    const u16* __restrict__ Qb, const u16* __restrict__ Kb,
    const u16* __restrict__ Vb, const int* __restrict__ evt,
    u16* __restrict__ Ob, const u16* __restrict__ Woh,
    float* __restrict__ Out)
{
    if (blockIdx.x < 512) {
        int fid = blockIdx.x;
        int bh = fid >> 4, j = (fid & 15) + 16;   // q-tiles 16..31
        flash_role(Qb, Kb, Vb, evt, Ob, bh, j * 64, j + 1);
    } else {
        int gid = blockIdx.x - 512;               // 0..127
        int bx = gid & 7, gy = gid >> 3;          // gy 0..15
        int yidx = (gy < 8) ? gy : gy + 8;        // rows {0..7,16..23}
        gemm_core<0>((const u16*)Ob, nullptr, Woh, nullptr, Out, bx, yidx * 128);
    }
}

// ---------------------------------------------------------------- launch
extern "C" void kernel_launch(void* const* d_in, const int* in_sizes, int n_in,
                              void* d_out, int out_size, void* d_ws, size_t ws_size,
                              hipStream_t stream)
{
    (void)in_sizes; (void)n_in; (void)out_size; (void)ws_size;
    const float* X  = (const float*)d_in[0];
    const float* Wq = (const float*)d_in[1];
    const float* Wk = (const float*)d_in[2];
    const float* Wv = (const float*)d_in[3];
    const float* Wo = (const float*)d_in[4];
    const float* gq = (const float*)d_in[5];
    const float* bq = (const float*)d_in[6];
    const float* gk = (const float*)d_in[7];
    const float* bk = (const float*)d_in[8];
    // d_in[9] cache_k, d_in[10] cache_v, d_in[11] start_pos: start_pos==0 here.

    char* p = (char*)d_ws;
    const size_t SZ_XH = (size_t)ROWS_ * D_ * 2;   // 8 MiB bf16
    const size_t SZ_W  = (size_t)D_ * D_ * 2;      // 2 MiB bf16
    const size_t SZ_Y  = (size_t)ROWS_ * D_ * 4;   // 16 MiB fp32
    const size_t SZ_PK = (size_t)ROWS_ * D_ * 2;   // 8 MiB bf16
    const size_t SZ_H0 = (size_t)ROWS_ * 64 * 4;   // 1 MiB fp32

    size_t o = 0;
    u16* Xhi = (u16*)(p + o); o += SZ_XH;
    u16* Xlo = (u16*)(p + o); o += SZ_XH;
    u16* Wqh = (u16*)(p + o); o += SZ_W;
    u16* Wql = (u16*)(p + o); o += SZ_W;
    u16* Wkh = (u16*)(p + o); o += SZ_W;
    u16* Wkl = (u16*)(p + o); o += SZ_W;
    u16* Wvh = (u16*)(p + o); o += SZ_W;
    u16* Woh = (u16*)(p + o); o += SZ_W;
    float* Yq = (float*)(p + o); size_t oYq = o; o += SZ_Y;
    float* Yk = (float*)(p + o); o += SZ_Y;
    float* Yv = (float*)(p + o); o += SZ_Y;
    u16* Qb = (u16*)(p + o); o += SZ_PK;
    u16* Kb = (u16*)(p + o); o += SZ_PK;
    u16* Vb = (u16*)(p + o); o += SZ_PK;
    float* q0s = (float*)(p + o); o += SZ_H0;
    float* k0s = (float*)(p + o); o += SZ_H0;
    float* Pp  = (float*)(p + o); o += (size_t)B_ * 8 * M_ * 4;
    int* evt   = (int*)(p + o);  o += (size_t)B_ * M_ * 4;
    // overlays (dead slots):
    float* S = (float*)(p + oYq);   // 32 MiB over Yq+Yk, used after LN
    u16* Ob  = Xhi;                 // 8 MiB over Xhi, used after all X-GEMMs

    cast_x_kernel<<<ROWS_ * D_ / (256 * 4), 256, 0, stream>>>(X, Xhi, Xlo);
    dim3 wgrid(32, 32), wblk(32, 32);
    cast_w_kernel<<<wgrid, wblk, 0, stream>>>(Wq, Wqh, Wql, 1);
    cast_w_kernel<<<wgrid, wblk, 0, stream>>>(Wk, Wkh, Wkl, 1);
    cast_w_kernel<<<wgrid, wblk, 0, stream>>>(Wv, Wvh, nullptr, 0);
    cast_w_kernel<<<wgrid, wblk, 0, stream>>>(Wo, Woh, nullptr, 0);

    dim3 ggrid(D_ / 128, ROWS_ / 128);
    gemm_kernel_t<1><<<ggrid, 256, 0, stream>>>(Xhi, Xlo, Wqh, Wql, Yq, 0);
    gemm_kernel_t<1><<<ggrid, 256, 0, stream>>>(Xhi, Xlo, Wkh, Wkl, Yk, 0);
    gemm_kernel_t<0><<<ggrid, 256, 0, stream>>>(Xhi, nullptr, Wvh, nullptr, Yv, 0);

    lnpack_kernel<<<ROWS_, 256, 0, stream>>>(Yq, gq, bq, Qb, q0s, 1);
    lnpack_kernel<<<ROWS_, 256, 0, stream>>>(Yk, gk, bk, Kb, k0s, 1);
    lnpack_kernel<<<ROWS_, 256, 0, stream>>>(Yv, nullptr, nullptr, Vb, nullptr, 0);

    s64_kernel<<<dim3(M_ / 64, N_ / 64, B_), 256, 0, stream>>>(q0s, k0s, S);
    p_kernel<<<dim3(M_ / 256, 8, B_), 256, 0, stream>>>(S, Pp);

    // evict (blocks 0,1) runs concurrently with flash q<1024 (blocks 2..513)
    fused_evict_flash1<<<514, 256, 0, stream>>>(S, Pp, evt, Qb, Kb, Vb, Ob);
    // flash q>=1024 (512 blocks) ∥ gemmO part 1 (128 blocks, Ob rows n<1024)
    fused_flash2_gemmo1<<<640, 256, 0, stream>>>(
        Qb, Kb, Vb, evt, Ob, Woh, (float*)d_out);
    // gemmO part 2 (rows n>=1024, needs flash2 output)
    gemm_kernel_t<0><<<dim3(8, 16), 256, 0, stream>>>(
        (const u16*)Ob, nullptr, Woh, nullptr, (float*)d_out, 2);
}

// Round 17
// 765.966 us; speedup vs baseline: 1.1354x; 1.0609x over previous
//
// MultiheadSelectiveAttentionWithTokenPruning — MI355X round 17 (= round 16 resubmit; infra failure, no data)
// (r15 base, +2 launch merges: QKV gemms in one launch (768 blocks, z-sel),
//  lnpack Q/K/V in one launch (y-sel). All data paths byte-identical.)
//
// Pipeline (all on `stream`, graph-capture safe, no statics):
//  1  cast_x      : X fp32 -> Xhi/Xlo bf16 (split for bf16x3 GEMM)
//  2  cast_w x4   : W fp32 -> W^T bf16 (hi[+lo for Wq/Wk])
//  3  gemm_qkv    : ONE launch: Yq=X@Wq (split), Yk=X@Wk (split),
//                   Yv=X@Wv (plain). 768 blocks; removes 2 full-device
//                   drain boundaries between 256-block gemms.
//  4  lnpack_all  : ONE launch: LN(Yq)->Qb+q0s, LN(Yk)->Kb+k0s, Yv->Vb.
//  5  s64_kernel  : S[b,n,m] = relu(q0s.k0s/8), 64x64 tiles (bit-identical)
//  6  p_kernel    : column partial sums of S rows 0..1023 (8 chunks)
//  7  FUSED       : evict (2 blocks, r9-proven 4-wave code) ∥ flash part 1
//                   (512 blocks, q<1024: prune mask vacuous). ~365 µs.
//  8  FUSED       : flash2 (q>=1024; 512 blocks) ∥ gemmO part 1 (128 blocks,
//                   Ob rows n<1024, final after launch 7).
//  9  gemmO part2 : row-blocks y in {8..15,24..31} (needs flash2's Ob rows).
//
// ws overlays: Ob reuses Xhi slot (dead after step 3); S reuses Yq+Yk slots
// (dead after step 4). Peak ws ~107.1 MB.

#include <hip/hip_runtime.h>

#define B_    2
#define N_    2048
#define D_    1024
#define H_    16
#define DH_   64
#define M_    2048
#define ROWS_ 4096
#define BUD_  1024

typedef unsigned short u16;
typedef unsigned int   u32;
typedef unsigned long long u64;
typedef __attribute__((ext_vector_type(8))) short short8;
typedef __attribute__((ext_vector_type(4))) float floatx4;

__device__ __forceinline__ u16 f2b(float f) {
    u32 u = __float_as_uint(f);
    return (u16)((u + 0x7FFFu + ((u >> 16) & 1u)) >> 16);   // RNE
}
__device__ __forceinline__ float b2f(u16 h) {
    return __uint_as_float(((u32)h) << 16);
}

// ---------------------------------------------------------------- cast X
__global__ __launch_bounds__(256) void cast_x_kernel(
    const float* __restrict__ X, u16* __restrict__ Xhi, u16* __restrict__ Xlo)
{
    int idx = (blockIdx.x * 256 + threadIdx.x) * 4;
    float4 v = *(const float4*)&X[idx];
    u16 h0 = f2b(v.x), h1 = f2b(v.y), h2 = f2b(v.z), h3 = f2b(v.w);
    ushort4 hv; hv.x = h0; hv.y = h1; hv.z = h2; hv.w = h3;
    *(ushort4*)&Xhi[idx] = hv;
    ushort4 lv;
    lv.x = f2b(v.x - b2f(h0)); lv.y = f2b(v.y - b2f(h1));
    lv.z = f2b(v.z - b2f(h2)); lv.w = f2b(v.w - b2f(h3));
    *(ushort4*)&Xlo[idx] = lv;
}

// ------------------------------------------------- cast + transpose W
__global__ __launch_bounds__(1024) void cast_w_kernel(
    const float* __restrict__ W, u16* __restrict__ Whi, u16* __restrict__ Wlo,
    int do_lo)
{
    __shared__ float tile[32][33];
    int tx = threadIdx.x, ty = threadIdx.y;
    int x = blockIdx.x * 32 + tx, y = blockIdx.y * 32 + ty;
    tile[ty][tx] = W[(size_t)y * D_ + x];
    __syncthreads();
    float v = tile[tx][ty];
    int n = blockIdx.x * 32 + ty, k = blockIdx.y * 32 + tx;
    u16 h = f2b(v);
    Whi[(size_t)n * D_ + k] = h;
    if (do_lo) Wlo[(size_t)n * D_ + k] = f2b(v - b2f(h));
}

// ------------------------------------------------------------- GEMM core
// C[row][col] = A[4096][1024] @ Bt^T  (Bt stored [n][k]); tile 128x128.
// MODE 1: C = Ah*Bh + Ah*Bl + Al*Bh  (bf16x3 split, ~fp32 precision)
template<int MODE>
__device__ void gemm_core(
    const u16* __restrict__ Ah, const u16* __restrict__ Al,
    const u16* __restrict__ Bh, const u16* __restrict__ Bl,
    float* __restrict__ C, int bx, int m0)
{
    __shared__ __align__(16) u16 sAh[128 * 32];
    __shared__ __align__(16) u16 sBh[128 * 32];
    __shared__ __align__(16) u16 sAl[MODE ? 128 * 32 : 8];
    __shared__ __align__(16) u16 sBl[MODE ? 128 * 32 : 8];
    int tid = threadIdx.x;
    int lane = tid & 63, wv = tid >> 6;
    int wr = wv >> 1, wc = wv & 1;
    int quad = lane >> 4, l16 = lane & 15;
    int n0 = bx * 128;

    floatx4 acc[4][4];
    floatx4 zero = {0.f, 0.f, 0.f, 0.f};
#pragma unroll
    for (int i = 0; i < 4; ++i)
#pragma unroll
        for (int j = 0; j < 4; ++j) acc[i][j] = zero;

    for (int k0 = 0; k0 < 1024; k0 += 32) {
#pragma unroll
        for (int it = 0; it < 2; ++it) {
            int e = (tid + it * 256) * 8;
            int r = e >> 5, c = e & 31;
            *(uint4*)&sAh[e] = *(const uint4*)&Ah[(size_t)(m0 + r) * 1024 + k0 + c];
            *(uint4*)&sBh[e] = *(const uint4*)&Bh[(size_t)(n0 + r) * 1024 + k0 + c];
            if (MODE) {
                *(uint4*)&sAl[e] = *(const uint4*)&Al[(size_t)(m0 + r) * 1024 + k0 + c];
                *(uint4*)&sBl[e] = *(const uint4*)&Bl[(size_t)(n0 + r) * 1024 + k0 + c];
            }
        }
        __syncthreads();
        short8 ah[4], al[4], bh[4], bl[4];
#pragma unroll
        for (int x = 0; x < 4; ++x) {
            int ra = (wr * 64 + x * 16 + l16) * 32 + quad * 8;
            int rb = (wc * 64 + x * 16 + l16) * 32 + quad * 8;
            ah[x] = *(const short8*)&sAh[ra];
            bh[x] = *(const short8*)&sBh[rb];
            if (MODE) {
                al[x] = *(const short8*)&sAl[ra];
                bl[x] = *(const short8*)&sBl[rb];
            }
        }
#pragma unroll
        for (int mi = 0; mi < 4; ++mi)
#pragma unroll
            for (int ni = 0; ni < 4; ++ni) {
                acc[mi][ni] = __builtin_amdgcn_mfma_f32_16x16x32_bf16(
                    ah[mi], bh[ni], acc[mi][ni], 0, 0, 0);
                if (MODE) {
                    acc[mi][ni] = __builtin_amdgcn_mfma_f32_16x16x32_bf16(
                        ah[mi], bl[ni], acc[mi][ni], 0, 0, 0);
                    acc[mi][ni] = __builtin_amdgcn_mfma_f32_16x16x32_bf16(
                        al[mi], bh[ni], acc[mi][ni], 0, 0, 0);
                }
            }
        __syncthreads();
    }
    // C/D layout: col = lane&15, row = (lane>>4)*4 + reg   [verified m89/m91]
#pragma unroll
    for (int mi = 0; mi < 4; ++mi)
#pragma unroll
        for (int ni = 0; ni < 4; ++ni)
#pragma unroll
            for (int r = 0; r < 4; ++r) {
                int row = m0 + wr * 64 + mi * 16 + quad * 4 + r;
                int col = n0 + wc * 64 + ni * 16 + l16;
                C[(size_t)row * 1024 + col] = acc[mi][ni][r];
            }
}

// ------------------- ONE launch for all three QKV gemms (z selects)
__global__ __launch_bounds__(256) void gemm_qkv_kernel(
    const u16* __restrict__ Xhi, const u16* __restrict__ Xlo,
    const u16* __restrict__ Wqh, const u16* __restrict__ Wql,
    const u16* __restrict__ Wkh, const u16* __restrict__ Wkl,
    const u16* __restrict__ Wvh,
    float* __restrict__ Yq, float* __restrict__ Yk, float* __restrict__ Yv)
{
    int m0 = blockIdx.y * 128;
    if (blockIdx.z == 0)
        gemm_core<1>(Xhi, Xlo, Wqh, Wql, Yq, blockIdx.x, m0);
    else if (blockIdx.z == 1)
        gemm_core<1>(Xhi, Xlo, Wkh, Wkl, Yk, blockIdx.x, m0);
    else
        gemm_core<0>(Xhi, nullptr, Wvh, nullptr, Yv, blockIdx.x, m0);
}

// standalone gemm launch (gemmO part 2). ymode 2: y'<8 -> y'+8, else y'+16.
template<int MODE>
__global__ __launch_bounds__(256) void gemm_kernel_t(
    const u16* __restrict__ Ah, const u16* __restrict__ Al,
    const u16* __restrict__ Bh, const u16* __restrict__ Bl,
    float* __restrict__ C, int ymode)
{
    int by = blockIdx.y;
    int yidx = (ymode == 0) ? by : ((by < 8) ? by + 8 : by + 16);
    gemm_core<MODE>(Ah, Al, Bh, Bl, C, blockIdx.x, yidx * 128);
}

// ------------------------------- LayerNorm + pack (ONE launch, y selects)
__global__ __launch_bounds__(256) void lnpack_all_kernel(
    const float* __restrict__ Yq, const float* __restrict__ Yk,
    const float* __restrict__ Yv,
    const float* __restrict__ gq, const float* __restrict__ bq,
    const float* __restrict__ gk, const float* __restrict__ bk,
    u16* __restrict__ Qb, u16* __restrict__ Kb, u16* __restrict__ Vb,
    float* __restrict__ q0s, float* __restrict__ k0s)
{
    const float* Y; const float* gamma; const float* beta;
    u16* Pk; float* head0; int do_ln;
    if (blockIdx.y == 0) { Y = Yq; gamma = gq; beta = bq; Pk = Qb; head0 = q0s; do_ln = 1; }
    else if (blockIdx.y == 1) { Y = Yk; gamma = gk; beta = bk; Pk = Kb; head0 = k0s; do_ln = 1; }
    else { Y = Yv; gamma = nullptr; beta = nullptr; Pk = Vb; head0 = nullptr; do_ln = 0; }

    int r = blockIdx.x;
    int tid = threadIdx.x;
    float4 v = *(const float4*)&Y[(size_t)r * D_ + tid * 4];
    float mu = 0.f, rsig = 1.f;
    __shared__ float sS[4], sQ[4];
    if (do_ln) {
        float s = v.x + v.y + v.z + v.w;
        float q = v.x * v.x + v.y * v.y + v.z * v.z + v.w * v.w;
#pragma unroll
        for (int d = 1; d < 64; d <<= 1) { s += __shfl_xor(s, d); q += __shfl_xor(q, d); }
        if ((tid & 63) == 0) { sS[tid >> 6] = s; sQ[tid >> 6] = q; }
        __syncthreads();
        s = sS[0] + sS[1] + sS[2] + sS[3];
        q = sQ[0] + sQ[1] + sQ[2] + sQ[3];
        mu = s * (1.f / 1024.f);
        float var = q * (1.f / 1024.f) - mu * mu;
        rsig = rsqrtf(var + 1e-5f);
    }
    int b = r >> 11, n = r & 2047;
    float xs[4] = {v.x, v.y, v.z, v.w};
#pragma unroll
    for (int j = 0; j < 4; ++j) {
        int c = tid * 4 + j;
        float val = do_ln ? ((xs[j] - mu) * rsig * gamma[c] + beta[c]) : xs[j];
        int h = c >> 6, dh = c & 63;
        Pk[(((size_t)b * H_ + h) * N_ + n) * DH_ + dh] = f2b(val);
        if (head0 && c < 64) head0[(size_t)r * 64 + c] = val;
    }
}

// ------------------------------------- head-0 selection scores S (64x64)
// Bit-identical to the 16x16 version: each output's dot product runs
// d = 0..63 ascending in a single fp32 FMA chain.
__global__ __launch_bounds__(256) void s64_kernel(
    const float* __restrict__ q0, const float* __restrict__ k0,
    float* __restrict__ S)
{
    int b = blockIdx.z;
    int n0 = blockIdx.y * 64, m0 = blockIdx.x * 64;
    int tid = threadIdx.x;
    int tx = tid & 15, ty = tid >> 4;
    floatx4 zero = {0.f, 0.f, 0.f, 0.f};
    if (m0 > n0 + 63) {                 // fully above diagonal -> zeros
#pragma unroll
        for (int i = 0; i < 4; ++i) {
            int n = n0 + 4 * ty + i;
            *(floatx4*)&S[((size_t)b * N_ + n) * M_ + m0 + 4 * tx] = zero;
        }
        return;
    }
    __shared__ float sq[64][65], sk[64][65];
    {
        int r = tid >> 2, cseg = (tid & 3) * 16;
        const float* qrow = &q0[((size_t)b * N_ + n0 + r) * 64 + cseg];
        const float* krow = &k0[((size_t)b * N_ + m0 + r) * 64 + cseg];
#pragma unroll
        for (int u = 0; u < 4; ++u) {
            float4 qa = *(const float4*)&qrow[u * 4];
            sq[r][cseg + u * 4 + 0] = qa.x; sq[r][cseg + u * 4 + 1] = qa.y;
            sq[r][cseg + u * 4 + 2] = qa.z; sq[r][cseg + u * 4 + 3] = qa.w;
            float4 ka = *(const float4*)&krow[u * 4];
            sk[r][cseg + u * 4 + 0] = ka.x; sk[r][cseg + u * 4 + 1] = ka.y;
            sk[r][cseg + u * 4 + 2] = ka.z; sk[r][cseg + u * 4 + 3] = ka.w;
        }
    }
    __syncthreads();
    float acc[4][4];
#pragma unroll
    for (int i = 0; i < 4; ++i)
#pragma unroll
        for (int j = 0; j < 4; ++j) acc[i][j] = 0.f;
#pragma unroll 8
    for (int d = 0; d < 64; ++d) {
        float qv[4], kv[4];
#pragma unroll
        for (int i = 0; i < 4; ++i) qv[i] = sq[4 * ty + i][d];
#pragma unroll
        for (int j = 0; j < 4; ++j) kv[j] = sk[4 * tx + j][d];
#pragma unroll
        for (int i = 0; i < 4; ++i)
#pragma unroll
            for (int j = 0; j < 4; ++j) acc[i][j] += qv[i] * kv[j];
    }
#pragma unroll
    for (int i = 0; i < 4; ++i) {
        int n = n0 + 4 * ty + i;
        floatx4 out;
#pragma unroll
        for (int j = 0; j < 4; ++j) {
            int m = m0 + 4 * tx + j;
            // causal m>n -> 0 ; diagonal m==n -> 0 ; col 0 -> 0
            out[j] = (m < n && m != 0) ? fmaxf(acc[i][j] * 0.125f, 0.f) : 0.f;
        }
        *(floatx4*)&S[((size_t)b * N_ + n) * M_ + m0 + 4 * tx] = out;
    }
}

// -------------------------------- partial column sums of S rows 0..1023
__global__ __launch_bounds__(256) void p_kernel(const float* __restrict__ S,
                                                float* __restrict__ P)
{
    int b = blockIdx.z, c = blockIdx.y;
    int m = blockIdx.x * 256 + threadIdx.x;
    const float* base = S + ((size_t)b * N_ + c * 128) * M_ + m;
    float s = 0.f;
    for (int j = 0; j < 128; ++j) s += base[(size_t)j * M_];
    P[((size_t)b * 8 + c) * M_ + m] = s;
}

// --------------------------------------------- sequential greedy eviction
// (r9-proven 4-wave code, byte-identical logic)
__device__ __forceinline__ void vsel(float& va, u32& la, float vb, u32 lb) {
    bool tk = vb > va;
    va = tk ? vb : va;
    la = tk ? lb : la;
}

template<int CTRL, int RMASK>
__device__ __forceinline__ void dpp_max_pack(float& v, u32& lo) {
    int hi = __float_as_int(v);
    int hi_o = __builtin_amdgcn_update_dpp(hi, hi, CTRL, RMASK, 0xF, false);
    int lo_o = __builtin_amdgcn_update_dpp((int)lo, (int)lo, CTRL, RMASK, 0xF, false);
    long long a = (long long)((((u64)(u32)hi) << 32) | lo);
    long long b = (long long)((((u64)(u32)hi_o) << 32) | (u32)lo_o);
    bool tk = b > a;
    v = tk ? __int_as_float(hi_o) : v;
    lo = tk ? (u32)lo_o : lo;
}

__device__ __forceinline__ void wave_argmax_to63(float& v, u32& lo) {
    dpp_max_pack<0x121, 0xF>(v, lo);   // row_ror:1
    dpp_max_pack<0x122, 0xF>(v, lo);   // row_ror:2
    dpp_max_pack<0x124, 0xF>(v, lo);   // row_ror:4
    dpp_max_pack<0x128, 0xF>(v, lo);   // row_ror:8
    dpp_max_pack<0x142, 0xA>(v, lo);   // row_bcast15 -> rows 1,3
    dpp_max_pack<0x143, 0xC>(v, lo);   // row_bcast31 -> rows 2,3
}

#define GLOAD(dst, voff, ptr, imm)                                    \
    asm volatile("global_load_dwordx4 %0, %1, %2 offset:" #imm        \
                 : "=v"(dst) : "v"(voff), "s"(ptr) : "memory")

#define ISSUE2(bank, row)                                             \
    {                                                                 \
        u32 r_ = (u32)((row) < 2047 ? (row) : 2047);                  \
        u32 vo = wbyte + r_ * 8192u;                                  \
        GLOAD(bank[0], vo, Sb, 0);                                    \
        GLOAD(bank[1], vo, Sb, 1024);                                 \
    }

#define VWAIT6()                                                      \
    do { asm volatile("s_waitcnt vmcnt(6)" ::: "memory");             \
         __builtin_amdgcn_sched_barrier(0); } while (0)
#define VWAIT0()                                                      \
    do { asm volatile("s_waitcnt vmcnt(0)" ::: "memory");             \
         __builtin_amdgcn_sched_barrier(0); } while (0)

__device__ __forceinline__ void evict_step4(
    int i, int t, int w, int par,
    const u32 (&lov)[2][4], float (&cum)[2][4], int (&evti)[2][4],
    const floatx4 (&bank)[2], uint2 (*spair)[4])
{
    const float NEGINF = __uint_as_float(0xFF800000u);
    // ---- per-wave (v, lo) tournament: ascending-index order, strict >
    float v0 = cum[0][0]; u32 l0 = lov[0][0];
    vsel(v0, l0, cum[0][1], lov[0][1]);
    float v1 = cum[0][2]; u32 l1 = lov[0][2];
    vsel(v1, l1, cum[0][3], lov[0][3]);
    vsel(v0, l0, v1, l1);
    float v2 = cum[1][0]; u32 l2 = lov[1][0];
    vsel(v2, l2, cum[1][1], lov[1][1]);
    float v3 = cum[1][2]; u32 l3 = lov[1][2];
    vsel(v3, l3, cum[1][3], lov[1][3]);
    vsel(v2, l2, v3, l3);
    vsel(v0, l0, v2, l2);
    wave_argmax_to63(v0, l0);
    // ---- cross-wave exchange (double-buffered by parity)
    if (t == 63) spair[par][w] = make_uint2(l0, (u32)__float_as_int(v0));
    asm volatile("s_waitcnt lgkmcnt(0)" ::: "memory");
    __builtin_amdgcn_sched_barrier(0);
    __builtin_amdgcn_s_barrier();      // raw barrier: no vmcnt drain
    __builtin_amdgcn_sched_barrier(0);
    uint2 q0 = spair[par][0], q1 = spair[par][1];
    uint2 q2 = spair[par][2], q3 = spair[par][3];
    long long k0 = (long long)((((u64)q0.y) << 32) | q0.x);
    long long k1 = (long long)((((u64)q1.y) << 32) | q1.x);
    long long k2 = (long long)((((u64)q2.y) << 32) | q2.x);
    long long k3 = (long long)((((u64)q3.y) << 32) | q3.x);
    long long ba = k0 > k1 ? k0 : k1;
    long long bb = k2 > k3 ? k2 : k3;
    long long bst = ba > bb ? ba : bb;   // packs unique (lo distinct)
    const u32 lostar = (u32)(bst & 0xFFFFFFFFll);
    // ---- update: Fm[i] -> Fm[i+1]
#pragma unroll
    for (int c = 0; c < 2; ++c) {
        cum[c][0] += bank[c][0]; cum[c][1] += bank[c][1];
        cum[c][2] += bank[c][2]; cum[c][3] += bank[c][3];
    }
    // ---- poison + record: branch-free, lostar uniform
#pragma unroll
    for (int c = 0; c < 2; ++c)
#pragma unroll
        for (int e = 0; e < 4; ++e) {
            bool hit = (lov[c][e] == lostar);
            cum[c][e] = hit ? NEGINF : cum[c][e];
            evti[c][e] = hit ? i : evti[c][e];
        }
}

__device__ void evict_role(const float* __restrict__ S,
                           const float* __restrict__ P,
                           int* __restrict__ evt)
{
    int b = blockIdx.x;
    int tid = threadIdx.x;
    int w = tid >> 6, t = tid & 63;            // 4 waves
    const float* Sb = S + (size_t)b * N_ * M_;
    int* evtb = evt + b * M_;
    const int mbase = 512 * w + 4 * t;
    const u32 wbyte = (u32)(2048 * w + 16 * t);  // byte offset within a row
    __shared__ uint2 spair[2][4];               // [parity][wave]
    u32 lov[2][4];
    int evti[2][4];
#pragma unroll
    for (int c = 0; c < 2; ++c)
#pragma unroll
        for (int e = 0; e < 4; ++e) {
            lov[c][e] = (u32)(2048 - (mbase + 256 * c + e));
            evti[c][e] = 0x3FFFFFFF;
        }
    // initial cum = column sums of the 8 partial chunks (same per-slot add
    // order as rounds 0-15 -> bitwise identical trajectories)
    float cum[2][4];
#pragma unroll
    for (int c = 0; c < 2; ++c) {
        float ax = 0.f, ay = 0.f, az = 0.f, aw = 0.f;
#pragma unroll
        for (int cc = 0; cc < 8; ++cc) {
            floatx4 pv = *(const floatx4*)&P[((size_t)b * 8 + cc) * M_ + mbase + 256 * c];
            ax += pv[0]; ay += pv[1]; az += pv[2]; aw += pv[3];
        }
        cum[c][0] = ax; cum[c][1] = ay; cum[c][2] = az; cum[c][3] = aw;
    }
    // fence: drain compiler-tracked loads so asm vmcnt counting is exact
    VWAIT0();
    floatx4 bA[2], bB[2], bC[2], bD[2];
    ISSUE2(bA, 1024)
    ISSUE2(bB, 1025)
    ISSUE2(bC, 1026)
    ISSUE2(bD, 1027)
#pragma unroll 1
    for (int ip = 1024; ip < 2048; ip += 4) {
        VWAIT6();
        evict_step4(ip + 0, t, w, 0, lov, cum, evti, bA, spair);
        ISSUE2(bA, ip + 4)
        VWAIT6();
        evict_step4(ip + 1, t, w, 1, lov, cum, evti, bB, spair);
        ISSUE2(bB, ip + 5)
        VWAIT6();
        evict_step4(ip + 2, t, w, 0, lov, cum, evti, bC, spair);
        ISSUE2(bC, ip + 6)
        VWAIT6();
        evict_step4(ip + 3, t, w, 1, lov, cum, evti, bD, spair);
        ISSUE2(bD, ip + 7)
    }
    VWAIT0();   // drain leftover bank loads before reusing the vmem queue
    // single coalesced write pass (the only global stores in this role)
#pragma unroll
    for (int c = 0; c < 2; ++c) {
        int4 o; o.x = evti[c][0]; o.y = evti[c][1];
        o.z = evti[c][2]; o.w = evti[c][3];
        *(int4*)&evtb[mbase + 256 * c] = o;
    }
}

// ------------------------------------------------------ flash attention
// role shared by fused launches (evtg==nullptr: q<1024, mask pure causal).
__device__ void flash_role(
    const u16* __restrict__ Qb, const u16* __restrict__ Kb,
    const u16* __restrict__ Vb, const int* __restrict__ evtg,
    u16* __restrict__ Ob, int bh, int q0, int ktiles)
{
    int b = bh >> 4, h = bh & 15;
    int tid = threadIdx.x, lane = tid & 63, w = tid >> 6;
    int quad = lane >> 4, l16 = lane & 15;
    const u16* Qh = Qb + (size_t)bh * N_ * DH_;
    const u16* Kh = Kb + (size_t)bh * N_ * DH_;
    const u16* Vh = Vb + (size_t)bh * N_ * DH_;
    __shared__ __align__(16) u16 sK[64 * 64];
    __shared__ __align__(16) u16 sV[64 * 64];     // transposed [dh][key]
    __shared__ __align__(16) u16 sP[4][16 * 64];  // wave-private P
    __shared__ int sevt[64];

    // Q A-frags in registers: A[m=lane&15][k=quad*8+j]
    short8 aq0 = *(const short8*)&Qh[(size_t)(q0 + w * 16 + l16) * 64 + quad * 8];
    short8 aq1 = *(const short8*)&Qh[(size_t)(q0 + w * 16 + l16) * 64 + quad * 8 + 32];

    floatx4 zero = {0.f, 0.f, 0.f, 0.f};
    floatx4 accO[4];
#pragma unroll
    for (int d = 0; d < 4; ++d) accO[d] = zero;
    float m_i[4] = {-1e30f, -1e30f, -1e30f, -1e30f};
    float l_i[4] = {0.f, 0.f, 0.f, 0.f};

    for (int kt = 0; kt < ktiles; ++kt) {
        int k0 = kt * 64;
#pragma unroll
        for (int it = 0; it < 2; ++it) {
            int e = (tid + it * 256) * 8;
            int r = e >> 6, c = e & 63;
            *(uint4*)&sK[e] = *(const uint4*)&Kh[(size_t)(k0 + r) * 64 + c];
            uint4 vv = *(const uint4*)&Vh[(size_t)(k0 + r) * 64 + c];
            sV[(c + 0) * 64 + r] = (u16)(vv.x & 0xFFFF);
            sV[(c + 1) * 64 + r] = (u16)(vv.x >> 16);
            sV[(c + 2) * 64 + r] = (u16)(vv.y & 0xFFFF);
            sV[(c + 3) * 64 + r] = (u16)(vv.y >> 16);
            sV[(c + 4) * 64 + r] = (u16)(vv.z & 0xFFFF);
            sV[(c + 5) * 64 + r] = (u16)(vv.z >> 16);
            sV[(c + 6) * 64 + r] = (u16)(vv.w & 0xFFFF);
            sV[(c + 7) * 64 + r] = (u16)(vv.w >> 16);
        }
        if (evtg && tid < 64) sevt[tid] = evtg[b * M_ + k0 + tid];
        __syncthreads();

        floatx4 lg[4];
        int nbase = q0 + w * 16 + quad * 4;
#pragma unroll
        for (int s = 0; s < 4; ++s) {
            floatx4 sc = zero;
            short8 bk0 = *(const short8*)&sK[(s * 16 + l16) * 64 + quad * 8];
            short8 bk1 = *(const short8*)&sK[(s * 16 + l16) * 64 + quad * 8 + 32];
            sc = __builtin_amdgcn_mfma_f32_16x16x32_bf16(aq0, bk0, sc, 0, 0, 0);
            sc = __builtin_amdgcn_mfma_f32_16x16x32_bf16(aq1, bk1, sc, 0, 0, 0);
            int m = k0 + s * 16 + l16;
            int ev = evtg ? sevt[s * 16 + l16] : 0x7FFFFFFF;
#pragma unroll
            for (int r = 0; r < 4; ++r) {
                int n = nbase + r;
                bool keep = (m <= n) && (n < ev);
                lg[s][r] = keep ? sc[r] * 0.125f : -1e30f;
            }
        }
        float mnew[4], scale[4], rs[4];
#pragma unroll
        for (int r = 0; r < 4; ++r) {
            float mx = fmaxf(fmaxf(lg[0][r], lg[1][r]), fmaxf(lg[2][r], lg[3][r]));
#pragma unroll
            for (int d = 1; d < 16; d <<= 1) mx = fmaxf(mx, __shfl_xor(mx, d));
            mnew[r] = fmaxf(m_i[r], mx);
            scale[r] = __expf(m_i[r] - mnew[r]);
            m_i[r] = mnew[r];
            rs[r] = 0.f;
        }
#pragma unroll
        for (int s = 0; s < 4; ++s)
#pragma unroll
            for (int r = 0; r < 4; ++r) {
                float p = __expf(lg[s][r] - mnew[r]);
                rs[r] += p;
                sP[w][(quad * 4 + r) * 64 + s * 16 + l16] = f2b(p);
            }
#pragma unroll
        for (int r = 0; r < 4; ++r) {
            float t_ = rs[r];
#pragma unroll
            for (int d = 1; d < 16; d <<= 1) t_ += __shfl_xor(t_, d);
            l_i[r] = l_i[r] * scale[r] + t_;
        }
#pragma unroll
        for (int dd = 0; dd < 4; ++dd) {
            accO[dd][0] *= scale[0]; accO[dd][1] *= scale[1];
            accO[dd][2] *= scale[2]; accO[dd][3] *= scale[3];
        }
        // P: C-layout -> A-layout via wave-private LDS round-trip
        short8 ap0 = *(const short8*)&sP[w][l16 * 64 + quad * 8];
        short8 ap1 = *(const short8*)&sP[w][l16 * 64 + quad * 8 + 32];
#pragma unroll
        for (int dd = 0; dd < 4; ++dd) {
            short8 bv0 = *(const short8*)&sV[(dd * 16 + l16) * 64 + quad * 8];
            short8 bv1 = *(const short8*)&sV[(dd * 16 + l16) * 64 + quad * 8 + 32];
            accO[dd] = __builtin_amdgcn_mfma_f32_16x16x32_bf16(ap0, bv0, accO[dd], 0, 0, 0);
            accO[dd] = __builtin_amdgcn_mfma_f32_16x16x32_bf16(ap1, bv1, accO[dd], 0, 0, 0);
        }
        __syncthreads();
    }
#pragma unroll
    for (int dd = 0; dd < 4; ++dd)
#pragma unroll
        for (int r = 0; r < 4; ++r) {
            int n = q0 + w * 16 + quad * 4 + r;
            int col = h * 64 + dd * 16 + l16;
            Ob[((size_t)b * N_ + n) * D_ + col] = f2b(accO[dd][r] / l_i[r]);
        }
}

// --------------------------- fused launch: evict ∥ flash part 1 (q<1024)
__global__ __launch_bounds__(256) void fused_evict_flash1(
    const float* __restrict__ S, const float* __restrict__ P,
    int* __restrict__ evt,
    const u16* __restrict__ Qb, const u16* __restrict__ Kb,
    const u16* __restrict__ Vb, u16* __restrict__ Ob)
{
    if (blockIdx.x < 2) {
        evict_role(S, P, evt);
    } else {
        int fid = blockIdx.x - 2;          // 0..511
        int bh = fid >> 4, j = fid & 15;   // q-tiles 0..15: n < 1024, no evt
        flash_role(Qb, Kb, Vb, nullptr, Ob, bh, j * 64, j + 1);
    }
}

// ---------------- fused launch: flash part 2 (q>=1024) ∥ gemmO part 1
// gemmO part 1 covers row-blocks y in {0..7, 16..23} = Ob rows n<1024,
// which are complete after fused_evict_flash1. Disjoint from flash2's
// writes (Ob rows n>=1024) -> no dependency, any dispatch order safe.
__global__ __launch_bounds__(256) void fused_flash2_gemmo1(
    const u16* __restrict__ Qb, const u16* __restrict__ Kb,
    const u16* __restrict__ Vb, const int* __restrict__ evt,
    u16* __restrict__ Ob, const u16* __restrict__ Woh,
    float* __restrict__ Out)
{
    if (blockIdx.x < 512) {
        int fid = blockIdx.x;
        int bh = fid >> 4, j = (fid & 15) + 16;   // q-tiles 16..31
        flash_role(Qb, Kb, Vb, evt, Ob, bh, j * 64, j + 1);
    } else {
        int gid = blockIdx.x - 512;               // 0..127
        int bx = gid & 7, gy = gid >> 3;          // gy 0..15
        int yidx = (gy < 8) ? gy : gy + 8;        // rows {0..7,16..23}
        gemm_core<0>((const u16*)Ob, nullptr, Woh, nullptr, Out, bx, yidx * 128);
    }
}

// ---------------------------------------------------------------- launch
extern "C" void kernel_launch(void* const* d_in, const int* in_sizes, int n_in,
                              void* d_out, int out_size, void* d_ws, size_t ws_size,
                              hipStream_t stream)
{
    (void)in_sizes; (void)n_in; (void)out_size; (void)ws_size;
    const float* X  = (const float*)d_in[0];
    const float* Wq = (const float*)d_in[1];
    const float* Wk = (const float*)d_in[2];
    const float* Wv = (const float*)d_in[3];
    const float* Wo = (const float*)d_in[4];
    const float* gq = (const float*)d_in[5];
    const float* bq = (const float*)d_in[6];
    const float* gk = (const float*)d_in[7];
    const float* bk = (const float*)d_in[8];
    // d_in[9] cache_k, d_in[10] cache_v, d_in[11] start_pos: start_pos==0 here.

    char* p = (char*)d_ws;
    const size_t SZ_XH = (size_t)ROWS_ * D_ * 2;   // 8 MiB bf16
    const size_t SZ_W  = (size_t)D_ * D_ * 2;      // 2 MiB bf16
    const size_t SZ_Y  = (size_t)ROWS_ * D_ * 4;   // 16 MiB fp32
    const size_t SZ_PK = (size_t)ROWS_ * D_ * 2;   // 8 MiB bf16
    const size_t SZ_H0 = (size_t)ROWS_ * 64 * 4;   // 1 MiB fp32

    size_t o = 0;
    u16* Xhi = (u16*)(p + o); o += SZ_XH;
    u16* Xlo = (u16*)(p + o); o += SZ_XH;
    u16* Wqh = (u16*)(p + o); o += SZ_W;
    u16* Wql = (u16*)(p + o); o += SZ_W;
    u16* Wkh = (u16*)(p + o); o += SZ_W;
    u16* Wkl = (u16*)(p + o); o += SZ_W;
    u16* Wvh = (u16*)(p + o); o += SZ_W;
    u16* Woh = (u16*)(p + o); o += SZ_W;
    float* Yq = (float*)(p + o); size_t oYq = o; o += SZ_Y;
    float* Yk = (float*)(p + o); o += SZ_Y;
    float* Yv = (float*)(p + o); o += SZ_Y;
    u16* Qb = (u16*)(p + o); o += SZ_PK;
    u16* Kb = (u16*)(p + o); o += SZ_PK;
    u16* Vb = (u16*)(p + o); o += SZ_PK;
    float* q0s = (float*)(p + o); o += SZ_H0;
    float* k0s = (float*)(p + o); o += SZ_H0;
    float* Pp  = (float*)(p + o); o += (size_t)B_ * 8 * M_ * 4;
    int* evt   = (int*)(p + o);  o += (size_t)B_ * M_ * 4;
    // overlays (dead slots):
    float* S = (float*)(p + oYq);   // 32 MiB over Yq+Yk, used after LN
    u16* Ob  = Xhi;                 // 8 MiB over Xhi, used after all X-GEMMs

    cast_x_kernel<<<ROWS_ * D_ / (256 * 4), 256, 0, stream>>>(X, Xhi, Xlo);
    dim3 wgrid(32, 32), wblk(32, 32);
    cast_w_kernel<<<wgrid, wblk, 0, stream>>>(Wq, Wqh, Wql, 1);
    cast_w_kernel<<<wgrid, wblk, 0, stream>>>(Wk, Wkh, Wkl, 1);
    cast_w_kernel<<<wgrid, wblk, 0, stream>>>(Wv, Wvh, nullptr, 0);
    cast_w_kernel<<<wgrid, wblk, 0, stream>>>(Wo, Woh, nullptr, 0);

    // all three QKV gemms in one launch (768 blocks, z selects)
    gemm_qkv_kernel<<<dim3(8, 32, 3), 256, 0, stream>>>(
        Xhi, Xlo, Wqh, Wql, Wkh, Wkl, Wvh, Yq, Yk, Yv);

    // all three lnpacks in one launch (y selects)
    lnpack_all_kernel<<<dim3(ROWS_, 3), 256, 0, stream>>>(
        Yq, Yk, Yv, gq, bq, gk, bk, Qb, Kb, Vb, q0s, k0s);

    s64_kernel<<<dim3(M_ / 64, N_ / 64, B_), 256, 0, stream>>>(q0s, k0s, S);
    p_kernel<<<dim3(M_ / 256, 8, B_), 256, 0, stream>>>(S, Pp);

    // evict (blocks 0,1) runs concurrently with flash q<1024 (blocks 2..513)
    fused_evict_flash1<<<514, 256, 0, stream>>>(S, Pp, evt, Qb, Kb, Vb, Ob);
    // flash q>=1024 (512 blocks) ∥ gemmO part 1 (128 blocks, Ob rows n<1024)
    fused_flash2_gemmo1<<<640, 256, 0, stream>>>(
        Qb, Kb, Vb, evt, Ob, Woh, (float*)d_out);
    // gemmO part 2 (rows n>=1024, needs flash2 output)
    gemm_kernel_t<0><<<dim3(8, 16), 256, 0, stream>>>(
        (const u16*)Ob, nullptr, Woh, nullptr, (float*)d_out, 2);
}